// Round 12
// baseline (715.802 us; speedup 1.0000x reference)
//
#include <hip/hip_runtime.h>
#include <cstdint>

#define H 128
static const int NG = 50000, NS = 20000, NP = 30000;

#define TG_RELU 2
#define TG_NORM 4
#define TG_OUTBF16 8

#define CSR_CHUNK 8192

typedef __attribute__((ext_vector_type(8))) short bf16x8;
typedef __attribute__((ext_vector_type(4))) float f32x4;
typedef __attribute__((ext_vector_type(2))) float v2f;

static inline int nblk(long long n) { return (int)((n + 255) / 256); }

__device__ inline unsigned short f2b(float f) {
  unsigned int u = __float_as_uint(f);
  u += 0x7FFFu + ((u >> 16) & 1u);
  return (unsigned short)(u >> 16);
}
__device__ inline float b2f(unsigned short u) {
  return __uint_as_float(((unsigned int)u) << 16);
}
__device__ inline float2 bfp2(unsigned int u) {
  return make_float2(__uint_as_float(u << 16), __uint_as_float(u & 0xFFFF0000u));
}
__device__ inline unsigned int f2bfp(float x, float y) {
  return ((unsigned int)f2b(y) << 16) | (unsigned int)f2b(x);
}
// fp8 e4m3 (OCP) hw-converters
__device__ inline float2 f8p2(unsigned short u) {
  v2f r = __builtin_amdgcn_cvt_pk_f32_fp8((int)(unsigned int)u, false);
  return make_float2(r.x, r.y);
}
__device__ inline unsigned char f2f8(float x) {
  int r = __builtin_amdgcn_cvt_pk_fp8_f32(x, 0.f, 0, false);
  return (unsigned char)(r & 0xFF);
}

// ================= atomic-free batched CSR build =================
struct Seg6 {
  const int* col[6];
  const int* row[6];
  const int* et0;
  int nodeoff[7];
  int edgeoff[7];
  int mode[6];         // 0=row, 1=row|(et<<16), 2=edge id (local)
  float addself[6];
  int hasdinv[6];
};

__global__ __launch_bounds__(256) void k_hist(Seg6 sg, int EE, int* __restrict__ table) {
  __shared__ int h[512];
  int tid = threadIdx.x, blk = blockIdx.x;
  h[tid] = 0; h[tid + 256] = 0;
  __syncthreads();
  int e0 = blk * CSR_CHUNK, e1 = min(EE, e0 + CSR_CHUNK);
  for (int e = e0 + tid; e < e1; e += 256) {
    int gi = 0;
    while (e >= sg.edgeoff[gi + 1]) gi++;
    int le = e - sg.edgeoff[gi];
    int gn = sg.nodeoff[gi] + sg.col[gi][le];
    atomicAdd(&h[gn >> 9], 1);  // LDS atomic
  }
  __syncthreads();
  table[blk * 512 + tid] = h[tid];
  table[blk * 512 + tid + 256] = h[tid + 256];
}

// per-bucket-column exclusive scan (parallel over 512 columns)
__global__ __launch_bounds__(256) void k_scanT1(int* __restrict__ table, int nblkA,
                                                int* __restrict__ colsum) {
  __shared__ int s[256];
  int b = blockIdx.x;
  int t = threadIdx.x;
  int v = (t < nblkA) ? table[t * 512 + b] : 0;
  s[t] = v;
  __syncthreads();
  for (int off = 1; off < 256; off <<= 1) {
    int x = s[t];
    int u = (t >= off) ? s[t - off] : 0;
    __syncthreads();
    s[t] = x + u;
    __syncthreads();
  }
  int excl = (t > 0) ? s[t - 1] : 0;
  if (t < nblkA) table[t * 512 + b] = excl;
  if (t == 255) colsum[b] = s[255];
}

__global__ void k_scanT2(const int* __restrict__ colsum, int* __restrict__ coarseOff) {
  __shared__ int cs[512];
  int b = threadIdx.x;
  cs[b] = colsum[b];
  __syncthreads();
  for (int off = 1; off < 512; off <<= 1) {
    int v = cs[b];
    int u = (b >= off) ? cs[b - off] : 0;
    __syncthreads();
    cs[b] = v + u;
    __syncthreads();
  }
  coarseOff[b] = (b > 0) ? cs[b - 1] : 0;
  if (b == 511) coarseOff[512] = cs[511];
}

__global__ void k_scanT3(int* __restrict__ table, const int* __restrict__ coarseOff, int n) {
  int i = blockIdx.x * blockDim.x + threadIdx.x;
  if (i < n) table[i] += coarseOff[i & 511];
}

__global__ __launch_bounds__(256) void k_scatterA(Seg6 sg, int EE, const int* __restrict__ table,
                                                  uint2* __restrict__ tmp) {
  __shared__ int cur[512];
  int tid = threadIdx.x, blk = blockIdx.x;
  cur[tid] = table[blk * 512 + tid];
  cur[tid + 256] = table[blk * 512 + tid + 256];
  __syncthreads();
  int e0 = blk * CSR_CHUNK, e1 = min(EE, e0 + CSR_CHUNK);
  for (int e = e0 + tid; e < e1; e += 256) {
    int gi = 0;
    while (e >= sg.edgeoff[gi + 1]) gi++;
    int le = e - sg.edgeoff[gi];
    int gn = sg.nodeoff[gi] + sg.col[gi][le];
    int m = sg.mode[gi];
    int pay;
    if (m == 2) pay = le;
    else {
      pay = sg.row[gi][le];
      if (m == 1) pay |= sg.et0[le] << 16;
    }
    int pos = atomicAdd(&cur[gn >> 9], 1);
    tmp[pos] = make_uint2((unsigned)gn, (unsigned)pay);
  }
}

__global__ __launch_bounds__(256) void k_localCSR(const uint2* __restrict__ tmp,
                                                  const int* __restrict__ coarseOff,
                                                  Seg6 sg, int NN, int EE, int B,
                                                  int* __restrict__ rowptr,
                                                  int* __restrict__ eidx,
                                                  float* __restrict__ dinv) {
  int b = blockIdx.x, tid = threadIdx.x;
  int base = b * 512;
  int nNodes = min(512, NN - base);
  int beg = coarseOff[b], end = coarseOff[b + 1];
  __shared__ int cnt[512];
  __shared__ int off[512];
  __shared__ int ps[256];
  cnt[tid] = 0; cnt[tid + 256] = 0;
  __syncthreads();
  for (int j = beg + tid; j < end; j += 256)
    atomicAdd(&cnt[tmp[j].x - base], 1);
  __syncthreads();
  int a = cnt[2 * tid], bb = cnt[2 * tid + 1];
  ps[tid] = a + bb;
  __syncthreads();
  for (int o = 1; o < 256; o <<= 1) {
    int v = ps[tid];
    int u = (tid >= o) ? ps[tid - o] : 0;
    __syncthreads();
    ps[tid] = v + u;
    __syncthreads();
  }
  int excl = (tid > 0) ? ps[tid - 1] : 0;
  off[2 * tid] = excl;
  off[2 * tid + 1] = excl + a;
  __syncthreads();
  for (int i = tid; i < nNodes; i += 256) {
    int gid = base + i;
    rowptr[gid] = beg + off[i];
    int gi = 0;
    while (gid >= sg.nodeoff[gi + 1]) gi++;
    if (sg.hasdinv[gi]) {
      float d = (float)cnt[i] + sg.addself[gi];
      dinv[gid] = (d > 0.f) ? rsqrtf(d) : 0.f;
    }
  }
  if (b == B - 1 && tid == 0) rowptr[NN] = EE;
  __syncthreads();
  for (int j = beg + tid; j < end; j += 256) {
    uint2 p = tmp[j];
    int pos = beg + atomicAdd(&off[p.x - base], 1);
    eidx[pos] = (int)p.y;
  }
}

// ================= weight pre-pack =================
struct PackD { const float* src; int Ksrc; int Kdst; };
struct Pack17 { PackD d[17]; int koff[18]; };

__global__ void k_pack(Pack17 p, unsigned short* __restrict__ Wt, int totalRows) {
  int t = blockIdx.x * blockDim.x + threadIdx.x;
  if (t >= totalRows * 128) return;
  int gk = t >> 7, n = t & 127;
  int w = 0;
  while (gk >= p.koff[w + 1]) w++;
  int k = gk - p.koff[w];
  float v = (k < p.d[w].Ksrc) ? p.d[w].src[(size_t)k * 128 + n] : 0.f;
  Wt[(size_t)p.koff[w] * 128 + (size_t)n * p.d[w].Kdst + k] = f2b(v);
}

// ================= wave-per-node gathers (no LDS, no syncs) =================
// bf16-source mean
__global__ __launch_bounds__(256) void k_gmean(const unsigned short* __restrict__ src,
                                               const int* __restrict__ eidx,
                                               const int* __restrict__ rowptr,
                                               unsigned short* __restrict__ out, int N) {
  int c = blockIdx.x * 4 + (threadIdx.x >> 6);
  if (c >= N) return;
  int lane = threadIdx.x & 63;
  int beg = rowptr[c], end = rowptr[c + 1];
  float2 A0 = {0.f, 0.f}, A1 = {0.f, 0.f}, A2 = {0.f, 0.f}, A3 = {0.f, 0.f};
  int j = beg;
  for (; j + 4 <= end; j += 4) {
    int e0 = eidx[j], e1 = eidx[j + 1], e2 = eidx[j + 2], e3 = eidx[j + 3];
    float2 v0 = bfp2(*(const unsigned int*)(src + (size_t)e0 * H + lane * 2));
    float2 v1 = bfp2(*(const unsigned int*)(src + (size_t)e1 * H + lane * 2));
    float2 v2 = bfp2(*(const unsigned int*)(src + (size_t)e2 * H + lane * 2));
    float2 v3 = bfp2(*(const unsigned int*)(src + (size_t)e3 * H + lane * 2));
    A0.x += v0.x; A0.y += v0.y;
    A1.x += v1.x; A1.y += v1.y;
    A2.x += v2.x; A2.y += v2.y;
    A3.x += v3.x; A3.y += v3.y;
  }
  for (; j < end; j++) {
    float2 v = bfp2(*(const unsigned int*)(src + (size_t)eidx[j] * H + lane * 2));
    A0.x += v.x; A0.y += v.y;
  }
  int cnt = end - beg;
  float s = 1.f / (float)(cnt > 0 ? cnt : 1);
  float ox = (A0.x + A1.x + A2.x + A3.x) * s;
  float oy = (A0.y + A1.y + A2.y + A3.y) * s;
  *(unsigned int*)(out + (size_t)c * H + lane * 2) = f2bfp(ox, oy);
}

// fp8-source mean (strided source)
__global__ __launch_bounds__(256) void k_gmean_f8(const unsigned char* __restrict__ src,
                                                  long ldS, int offS,
                                                  const int* __restrict__ eidx,
                                                  const int* __restrict__ rowptr,
                                                  unsigned short* __restrict__ out, int N) {
  int c = blockIdx.x * 4 + (threadIdx.x >> 6);
  if (c >= N) return;
  int lane = threadIdx.x & 63;
  int beg = rowptr[c], end = rowptr[c + 1];
  float2 A0 = {0.f, 0.f}, A1 = {0.f, 0.f}, A2 = {0.f, 0.f}, A3 = {0.f, 0.f};
  int j = beg;
  for (; j + 4 <= end; j += 4) {
    int e0 = eidx[j], e1 = eidx[j + 1], e2 = eidx[j + 2], e3 = eidx[j + 3];
    float2 v0 = f8p2(*(const unsigned short*)(src + (size_t)e0 * ldS + offS + lane * 2));
    float2 v1 = f8p2(*(const unsigned short*)(src + (size_t)e1 * ldS + offS + lane * 2));
    float2 v2 = f8p2(*(const unsigned short*)(src + (size_t)e2 * ldS + offS + lane * 2));
    float2 v3 = f8p2(*(const unsigned short*)(src + (size_t)e3 * ldS + offS + lane * 2));
    A0.x += v0.x; A0.y += v0.y;
    A1.x += v1.x; A1.y += v1.y;
    A2.x += v2.x; A2.y += v2.y;
    A3.x += v3.x; A3.y += v3.y;
  }
  for (; j < end; j++) {
    float2 v = f8p2(*(const unsigned short*)(src + (size_t)eidx[j] * ldS + offS + lane * 2));
    A0.x += v.x; A0.y += v.y;
  }
  int cnt = end - beg;
  float s = 1.f / (float)(cnt > 0 ? cnt : 1);
  float ox = (A0.x + A1.x + A2.x + A3.x) * s;
  float oy = (A0.y + A1.y + A2.y + A3.y) * s;
  *(unsigned int*)(out + (size_t)c * H + lane * 2) = f2bfp(ox, oy);
}

// 3-relation mean (fp8 source, 4-unrolled) -> concatenated 384-wide bf16 row
__global__ __launch_bounds__(256) void k_grel3(const unsigned char* __restrict__ src,
                                               const int* __restrict__ eidx,
                                               const int* __restrict__ rowptr,
                                               unsigned short* __restrict__ G3, int N) {
  int c = blockIdx.x * 4 + (threadIdx.x >> 6);
  if (c >= N) return;
  int lane = threadIdx.x & 63;
  int beg = rowptr[c], end = rowptr[c + 1];
  float2 a0 = {0.f, 0.f}, a1 = {0.f, 0.f}, a2 = {0.f, 0.f};
  int c0 = 0, c1 = 0, c2 = 0;
  int j = beg;
  for (; j + 4 <= end; j += 4) {
    int p0 = eidx[j], p1 = eidx[j + 1], p2 = eidx[j + 2], p3 = eidx[j + 3];
    float2 w0 = f8p2(*(const unsigned short*)(src + (size_t)(p0 & 0xFFFF) * H + lane * 2));
    float2 w1 = f8p2(*(const unsigned short*)(src + (size_t)(p1 & 0xFFFF) * H + lane * 2));
    float2 w2 = f8p2(*(const unsigned short*)(src + (size_t)(p2 & 0xFFFF) * H + lane * 2));
    float2 w3 = f8p2(*(const unsigned short*)(src + (size_t)(p3 & 0xFFFF) * H + lane * 2));
    int r0 = p0 >> 16, r1 = p1 >> 16, r2 = p2 >> 16, r3 = p3 >> 16;
    if (r0 == 0) { a0.x += w0.x; a0.y += w0.y; c0++; }
    else if (r0 == 1) { a1.x += w0.x; a1.y += w0.y; c1++; }
    else { a2.x += w0.x; a2.y += w0.y; c2++; }
    if (r1 == 0) { a0.x += w1.x; a0.y += w1.y; c0++; }
    else if (r1 == 1) { a1.x += w1.x; a1.y += w1.y; c1++; }
    else { a2.x += w1.x; a2.y += w1.y; c2++; }
    if (r2 == 0) { a0.x += w2.x; a0.y += w2.y; c0++; }
    else if (r2 == 1) { a1.x += w2.x; a1.y += w2.y; c1++; }
    else { a2.x += w2.x; a2.y += w2.y; c2++; }
    if (r3 == 0) { a0.x += w3.x; a0.y += w3.y; c0++; }
    else if (r3 == 1) { a1.x += w3.x; a1.y += w3.y; c1++; }
    else { a2.x += w3.x; a2.y += w3.y; c2++; }
  }
  for (; j < end; j++) {
    int pk = eidx[j];
    int rel = pk >> 16;
    float2 v = f8p2(*(const unsigned short*)(src + (size_t)(pk & 0xFFFF) * H + lane * 2));
    if (rel == 0) { a0.x += v.x; a0.y += v.y; c0++; }
    else if (rel == 1) { a1.x += v.x; a1.y += v.y; c1++; }
    else { a2.x += v.x; a2.y += v.y; c2++; }
  }
  float s0 = 1.f / (float)(c0 > 0 ? c0 : 1);
  float s1 = 1.f / (float)(c1 > 0 ? c1 : 1);
  float s2 = 1.f / (float)(c2 > 0 ? c2 : 1);
  size_t base = (size_t)c * 384 + lane * 2;
  *(unsigned int*)(G3 + base) = f2bfp(a0.x * s0, a0.y * s0);
  *(unsigned int*)(G3 + base + 128) = f2bfp(a1.x * s1, a1.y * s1);
  *(unsigned int*)(G3 + base + 256) = f2bfp(a2.x * s2, a2.y * s2);
}

// symmetric-normalized gather (+ optional self + bias + relu), strided bf16
__global__ __launch_bounds__(256) void k_gnorm(const unsigned short* __restrict__ src,
                                               long ldS, int offS,
                                               const int* __restrict__ eidx,
                                               const int* __restrict__ rowptr,
                                               const float* __restrict__ dinv,
                                               const unsigned short* __restrict__ selfX,
                                               const float* __restrict__ bias,
                                               unsigned short* __restrict__ out,
                                               long ldD, int offD, int relu, int N) {
  int c = blockIdx.x * 4 + (threadIdx.x >> 6);
  if (c >= N) return;
  int lane = threadIdx.x & 63;
  int beg = rowptr[c], end = rowptr[c + 1];
  float2 A0 = {0.f, 0.f}, A1 = {0.f, 0.f}, A2 = {0.f, 0.f}, A3 = {0.f, 0.f};
  int j = beg;
  for (; j + 4 <= end; j += 4) {
    int e0 = eidx[j], e1 = eidx[j + 1], e2 = eidx[j + 2], e3 = eidx[j + 3];
    float w0 = dinv[e0], w1 = dinv[e1], w2 = dinv[e2], w3 = dinv[e3];
    float2 v0 = bfp2(*(const unsigned int*)(src + (size_t)e0 * ldS + offS + lane * 2));
    float2 v1 = bfp2(*(const unsigned int*)(src + (size_t)e1 * ldS + offS + lane * 2));
    float2 v2 = bfp2(*(const unsigned int*)(src + (size_t)e2 * ldS + offS + lane * 2));
    float2 v3 = bfp2(*(const unsigned int*)(src + (size_t)e3 * ldS + offS + lane * 2));
    A0.x = fmaf(w0, v0.x, A0.x); A0.y = fmaf(w0, v0.y, A0.y);
    A1.x = fmaf(w1, v1.x, A1.x); A1.y = fmaf(w1, v1.y, A1.y);
    A2.x = fmaf(w2, v2.x, A2.x); A2.y = fmaf(w2, v2.y, A2.y);
    A3.x = fmaf(w3, v3.x, A3.x); A3.y = fmaf(w3, v3.y, A3.y);
  }
  for (; j < end; j++) {
    int e = eidx[j];
    float w = dinv[e];
    float2 v = bfp2(*(const unsigned int*)(src + (size_t)e * ldS + offS + lane * 2));
    A0.x = fmaf(w, v.x, A0.x); A0.y = fmaf(w, v.y, A0.y);
  }
  float dc = dinv[c];
  float ox = (A0.x + A1.x + A2.x + A3.x) * dc;
  float oy = (A0.y + A1.y + A2.y + A3.y) * dc;
  if (selfX) {
    float2 sv = bfp2(*(const unsigned int*)(selfX + (size_t)c * H + lane * 2));
    ox += dc * dc * sv.x;
    oy += dc * dc * sv.y;
  }
  if (bias) {
    float2 bv = *(const float2*)(bias + lane * 2);
    ox += bv.x; oy += bv.y;
  }
  if (relu) { ox = fmaxf(ox, 0.f); oy = fmaxf(oy, 0.f); }
  *(unsigned int*)(out + (size_t)c * ldD + offD + lane * 2) = f2bfp(ox, oy);
}

// fused ResGated + hh-mean: interleaved fp8 qvg rows (q@0, v@128, g@256; ld=384)
__global__ __launch_bounds__(256) void k_resgated_mean(const unsigned short* __restrict__ kk,
                                                       const unsigned char* __restrict__ qvg,
                                                       const float* __restrict__ ea,
                                                       const float* __restrict__ We,
                                                       const int* __restrict__ rh,
                                                       const int* __restrict__ eidx,
                                                       const int* __restrict__ rowptr,
                                                       const float* __restrict__ sx,
                                                       const float* __restrict__ Wsk,
                                                       const float* __restrict__ rgb,
                                                       unsigned short* __restrict__ outS,
                                                       unsigned short* __restrict__ outM, int N) {
  int c = blockIdx.x * 4 + (threadIdx.x >> 6);
  if (c >= N) return;
  int lane = threadIdx.x & 63;
  int d0 = lane * 2;
  int beg = rowptr[c], end = rowptr[c + 1];
  float2 kload = bfp2(*(const unsigned int*)(kk + (size_t)c * H + d0));
  float2 we0 = make_float2(We[d0], We[d0 + 1]);
  float2 we1 = make_float2(We[H + d0], We[H + d0 + 1]);
  float2 accS = {0.f, 0.f}, accM = {0.f, 0.f};
  int j = beg;
  for (; j + 4 <= end; j += 4) {
    int e0 = eidx[j], e1 = eidx[j + 1], e2 = eidx[j + 2], e3 = eidx[j + 3];
    int r0 = rh[e0], r1 = rh[e1], r2 = rh[e2], r3 = rh[e3];
    float2 ea0 = *(const float2*)(ea + 2 * e0);
    float2 ea1 = *(const float2*)(ea + 2 * e1);
    float2 ea2 = *(const float2*)(ea + 2 * e2);
    float2 ea3 = *(const float2*)(ea + 2 * e3);
    const unsigned char* b0 = qvg + (size_t)r0 * 384 + d0;
    const unsigned char* b1 = qvg + (size_t)r1 * 384 + d0;
    const unsigned char* b2 = qvg + (size_t)r2 * 384 + d0;
    const unsigned char* b3 = qvg + (size_t)r3 * 384 + d0;
    unsigned short uq0 = *(const unsigned short*)(b0);
    unsigned short uv0 = *(const unsigned short*)(b0 + 128);
    unsigned short ug0 = *(const unsigned short*)(b0 + 256);
    unsigned short uq1 = *(const unsigned short*)(b1);
    unsigned short uv1 = *(const unsigned short*)(b1 + 128);
    unsigned short ug1 = *(const unsigned short*)(b1 + 256);
    unsigned short uq2 = *(const unsigned short*)(b2);
    unsigned short uv2 = *(const unsigned short*)(b2 + 128);
    unsigned short ug2 = *(const unsigned short*)(b2 + 256);
    unsigned short uq3 = *(const unsigned short*)(b3);
    unsigned short uv3 = *(const unsigned short*)(b3 + 128);
    unsigned short ug3 = *(const unsigned short*)(b3 + 256);
#define RG_STEP(UQ, UV, UG, EA)                                            \
    {                                                                      \
      float2 qv = f8p2(UQ);                                                \
      float2 vv = f8p2(UV);                                                \
      float2 gv = f8p2(UG);                                                \
      float x0 = kload.x + qv.x + (EA).x * we0.x + (EA).y * we1.x;         \
      float x1 = kload.y + qv.y + (EA).x * we0.y + (EA).y * we1.y;         \
      float eta0 = 1.f / (1.f + __expf(-x0));                              \
      float eta1 = 1.f / (1.f + __expf(-x1));                              \
      accS.x = fmaf(eta0, vv.x, accS.x);                                   \
      accS.y = fmaf(eta1, vv.y, accS.y);                                   \
      accM.x += gv.x; accM.y += gv.y;                                      \
    }
    RG_STEP(uq0, uv0, ug0, ea0)
    RG_STEP(uq1, uv1, ug1, ea1)
    RG_STEP(uq2, uv2, ug2, ea2)
    RG_STEP(uq3, uv3, ug3, ea3)
  }
  for (; j < end; j++) {
    int e = eidx[j];
    int r = rh[e];
    float2 eav = *(const float2*)(ea + 2 * e);
    const unsigned char* bp = qvg + (size_t)r * 384 + d0;
    unsigned short uq = *(const unsigned short*)(bp);
    unsigned short uv = *(const unsigned short*)(bp + 128);
    unsigned short ug = *(const unsigned short*)(bp + 256);
    RG_STEP(uq, uv, ug, eav)
  }
#undef RG_STEP
  float sk0 = rgb[d0], sk1 = rgb[d0 + 1];
#pragma unroll
  for (int f = 0; f < 6; f++) {
    float xf = sx[c * 6 + f];
    sk0 = fmaf(xf, Wsk[f * H + d0], sk0);
    sk1 = fmaf(xf, Wsk[f * H + d0 + 1], sk1);
  }
  *(unsigned int*)(outS + (size_t)c * H + d0) =
      f2bfp(fmaxf(accS.x + sk0, 0.f), fmaxf(accS.y + sk1, 0.f));
  int cnt = end - beg;
  float s = 1.f / (float)(cnt > 0 ? cnt : 1);
  *(unsigned int*)(outM + (size_t)c * H + d0) = f2bfp(accM.x * s, accM.y * s);
}

// 7-dim symmetric-normalized gather, wave-per-node: 64 lanes = 8 edge-groups x 8 features
__global__ __launch_bounds__(256) void k_gnorm7w(const unsigned short* __restrict__ src,
                                                 int ldS, int offS,
                                                 const int* __restrict__ eidx,
                                                 const int* __restrict__ rowptr,
                                                 const float* __restrict__ dinv,
                                                 unsigned short* __restrict__ dst,
                                                 int ldD, int offD, int N) {
  int c = blockIdx.x * 4 + (threadIdx.x >> 6);
  if (c >= N) return;
  int lane = threadIdx.x & 63;
  int eg = lane >> 3, f = lane & 7;
  int beg = rowptr[c], end = rowptr[c + 1];
  float acc = 0.f;
  for (int j = beg + eg; j < end; j += 8) {
    int r = eidx[j] & 0xFFFF;
    float w = dinv[r];
    float val = (f < 7) ? b2f(src[(size_t)r * ldS + offS + f]) : 0.f;
    acc = fmaf(w, val, acc);
  }
  acc += __shfl_xor(acc, 8);
  acc += __shfl_xor(acc, 16);
  acc += __shfl_xor(acc, 32);
  if (eg == 0 && f < 7)
    dst[(size_t)c * ldD + offD + f] = f2b(acc * dinv[c]);
}

// ================= small utilities =================
// zero-fills full 32-wide row (cols 7..31 = 0) -> kills the memset dispatch
__global__ void k_copy7b(const float* __restrict__ src, unsigned short* __restrict__ dst, int n) {
  long long t = (long long)blockIdx.x * blockDim.x + threadIdx.x;
  int i = (int)(t >> 5), f = (int)(t & 31);
  if (i < n) dst[(size_t)i * 32 + f] = (f < 7) ? f2b(src[(size_t)i * 7 + f]) : 0;
}

__global__ void k_gemm128b(const float* __restrict__ X, const float* __restrict__ W,
                           const float* __restrict__ b, unsigned short* __restrict__ out,
                           int M, int K) {
  long long t = (long long)blockIdx.x * blockDim.x + threadIdx.x;
  if (t >= (long long)M * H) return;
  int i = (int)(t >> 7), h = (int)(t & 127);
  float acc = b ? b[h] : 0.f;
  const float* x = X + (long long)i * K;
  for (int k = 0; k < K; k++) acc = fmaf(x[k], W[k * H + h], acc);
  out[t] = f2b(acc);
}

// ================= MFMA bf16 GEMM: C[M x 128] = [X1|X2] @ [W1;W2] =================
// optional C8: fp8 e4m3 copy of the output with its own row stride ldC8
__global__ __launch_bounds__(256) void k_mgemm(const unsigned short* __restrict__ X1, int ldX1, int K1,
                                               const unsigned short* __restrict__ W1t,
                                               const unsigned short* __restrict__ X2, int ldX2, int K2,
                                               const unsigned short* __restrict__ W2t,
                                               const float* __restrict__ bias,
                                               void* __restrict__ Cv, long ldC,
                                               int M, int flags,
                                               unsigned char* __restrict__ C8, long ldC8) {
  __shared__ unsigned short Als[64 * 40];
  __shared__ unsigned short Bls[128 * 40];
  __shared__ float rs[2][64];
  int tid = threadIdx.x;
  int lane = tid & 63, wv = tid >> 6;
  int m = lane & 15, q = lane >> 4;
  int rbase = (wv & 1) * 32;
  int cbase = (wv >> 1) * 64;
  int blockRow = blockIdx.x * 64;
  int sr = tid >> 2, skc = (tid & 3) * 8;
  f32x4 acc[2][4];
#pragma unroll
  for (int a = 0; a < 2; a++)
#pragma unroll
    for (int b = 0; b < 4; b++) acc[a][b] = (f32x4){0.f, 0.f, 0.f, 0.f};

  int Ktot = K1 + K2;
  for (int k0 = 0; k0 < Ktot; k0 += 32) {
    const unsigned short* Xb;
    const unsigned short* Wt_;
    int kr, ldx, Kw;
    if (k0 < K1) { Xb = X1; Wt_ = W1t; kr = k0; ldx = ldX1; Kw = K1; }
    else { Xb = X2; Wt_ = W2t; kr = k0 - K1; ldx = ldX2; Kw = K2; }
    __syncthreads();
    {
      int gr = blockRow + sr;
      bf16x8 xv = (bf16x8){0, 0, 0, 0, 0, 0, 0, 0};
      if (gr < M) xv = *(const bf16x8*)(Xb + (size_t)gr * ldx + kr + skc);
      *(bf16x8*)&Als[sr * 40 + skc] = xv;
    }
#pragma unroll
    for (int it = 0; it < 2; it++) {
      int fid = it * 256 + tid;
      int n = fid >> 2, kc = (fid & 3) * 8;
      *(bf16x8*)&Bls[n * 40 + kc] = *(const bf16x8*)(Wt_ + (size_t)n * Kw + kr + kc);
    }
    __syncthreads();
    bf16x8 a0 = *(const bf16x8*)&Als[(rbase + m) * 40 + q * 8];
    bf16x8 a1 = *(const bf16x8*)&Als[(rbase + 16 + m) * 40 + q * 8];
    bf16x8 b0 = *(const bf16x8*)&Bls[(cbase + m) * 40 + q * 8];
    bf16x8 b1 = *(const bf16x8*)&Bls[(cbase + 16 + m) * 40 + q * 8];
    bf16x8 b2 = *(const bf16x8*)&Bls[(cbase + 32 + m) * 40 + q * 8];
    bf16x8 b3 = *(const bf16x8*)&Bls[(cbase + 48 + m) * 40 + q * 8];
    acc[0][0] = __builtin_amdgcn_mfma_f32_16x16x32_bf16(a0, b0, acc[0][0], 0, 0, 0);
    acc[0][1] = __builtin_amdgcn_mfma_f32_16x16x32_bf16(a0, b1, acc[0][1], 0, 0, 0);
    acc[0][2] = __builtin_amdgcn_mfma_f32_16x16x32_bf16(a0, b2, acc[0][2], 0, 0, 0);
    acc[0][3] = __builtin_amdgcn_mfma_f32_16x16x32_bf16(a0, b3, acc[0][3], 0, 0, 0);
    acc[1][0] = __builtin_amdgcn_mfma_f32_16x16x32_bf16(a1, b0, acc[1][0], 0, 0, 0);
    acc[1][1] = __builtin_amdgcn_mfma_f32_16x16x32_bf16(a1, b1, acc[1][1], 0, 0, 0);
    acc[1][2] = __builtin_amdgcn_mfma_f32_16x16x32_bf16(a1, b2, acc[1][2], 0, 0, 0);
    acc[1][3] = __builtin_amdgcn_mfma_f32_16x16x32_bf16(a1, b3, acc[1][3], 0, 0, 0);
  }
  float ov[2][4][4];
  float bcol[4] = {0.f, 0.f, 0.f, 0.f};
  if (bias) {
#pragma unroll
    for (int j = 0; j < 4; j++) bcol[j] = bias[cbase + j * 16 + m];
  }
#pragma unroll
  for (int a = 0; a < 2; a++)
#pragma unroll
    for (int j = 0; j < 4; j++)
#pragma unroll
      for (int i = 0; i < 4; i++) ov[a][j][i] = acc[a][j][i] + bcol[j];

  if (flags & TG_NORM) {
#pragma unroll
    for (int a = 0; a < 2; a++)
#pragma unroll
      for (int i = 0; i < 4; i++) {
        float p = 0.f;
#pragma unroll
        for (int j = 0; j < 4; j++) p = fmaf(ov[a][j][i], ov[a][j][i], p);
        p += __shfl_xor(p, 1);
        p += __shfl_xor(p, 2);
        p += __shfl_xor(p, 4);
        p += __shfl_xor(p, 8);
        if (m == 0) rs[wv >> 1][rbase + a * 16 + q * 4 + i] = p;
      }
    __syncthreads();
#pragma unroll
    for (int a = 0; a < 2; a++)
#pragma unroll
      for (int i = 0; i < 4; i++) {
        int ridx = rbase + a * 16 + q * 4 + i;
        float s = rs[0][ridx] + rs[1][ridx];
        float f = 1.f / fmaxf(sqrtf(s), 1e-12f);
#pragma unroll
        for (int j = 0; j < 4; j++) ov[a][j][i] = fmaxf(ov[a][j][i] * f, 0.f);
      }
  } else if (flags & TG_RELU) {
#pragma unroll
    for (int a = 0; a < 2; a++)
#pragma unroll
      for (int j = 0; j < 4; j++)
#pragma unroll
        for (int i = 0; i < 4; i++) ov[a][j][i] = fmaxf(ov[a][j][i], 0.f);
  }
  if (flags & TG_OUTBF16) {
    unsigned short* C = (unsigned short*)Cv;
#pragma unroll
    for (int a = 0; a < 2; a++)
#pragma unroll
      for (int i = 0; i < 4; i++) {
        int row = blockRow + rbase + a * 16 + q * 4 + i;
        if (row < M) {
#pragma unroll
          for (int j = 0; j < 4; j++)
            C[(size_t)row * ldC + cbase + j * 16 + m] = f2b(ov[a][j][i]);
        }
      }
  } else {
    float* C = (float*)Cv;
#pragma unroll
    for (int a = 0; a < 2; a++)
#pragma unroll
      for (int i = 0; i < 4; i++) {
        int row = blockRow + rbase + a * 16 + q * 4 + i;
        if (row < M) {
#pragma unroll
          for (int j = 0; j < 4; j++)
            C[(size_t)row * ldC + cbase + j * 16 + m] = ov[a][j][i];
        }
      }
  }
  if (C8) {
#pragma unroll
    for (int a = 0; a < 2; a++)
#pragma unroll
      for (int i = 0; i < 4; i++) {
        int row = blockRow + rbase + a * 16 + q * 4 + i;
        if (row < M) {
#pragma unroll
          for (int j = 0; j < 4; j++)
            C8[(size_t)row * ldC8 + cbase + j * 16 + m] = f2f8(ov[a][j][i]);
        }
      }
  }
}

static inline int mgb(int M) { return (M + 63) / 64; }

// ================= fused head =================
__global__ __launch_bounds__(256) void k_head(const float* __restrict__ X,
                                              const float* __restrict__ lw,
                                              const float* __restrict__ lb,
                                              const float* __restrict__ lwl,
                                              const float* __restrict__ lbl,
                                              float* __restrict__ z, int M) {
  __shared__ float Wl[128 * 32];
  __shared__ float Xs[8][128];
  int tid = threadIdx.x;
  for (int i = tid * 4; i < 4096; i += 1024) *(float4*)&Wl[i] = *(const float4*)&lw[i];
  int rowBase = blockIdx.x * 8;
  {
    int idx = tid * 4;
    int xr = idx >> 7, xc = idx & 127;
    int grow = rowBase + xr;
    float4 v = make_float4(0.f, 0.f, 0.f, 0.f);
    if (grow < M) v = *(const float4*)(X + (size_t)grow * H + xc);
    *(float4*)&Xs[xr][xc] = v;
  }
  __syncthreads();
  int r = tid >> 5, o = tid & 31;
  float acc = lb[o];
  for (int k = 0; k < 128; k++) acc = fmaf(Xs[r][k], Wl[k * 32 + o], acc);
  acc = fmaxf(acc, 0.f) * lwl[o];
  for (int s = 16; s > 0; s >>= 1) acc += __shfl_down(acc, s, 32);
  int grow = rowBase + r;
  if (o == 0 && grow < M) z[grow] = acc + lbl[0];
}

// ================= log_softmax =================
__global__ void k_logsoftmax(const float* __restrict__ z, float* __restrict__ out, int n) {
  __shared__ float red[256];
  int tid = threadIdx.x;
  float m = -1e30f;
  for (int i = tid; i < n; i += 256) m = fmaxf(m, z[i]);
  red[tid] = m;
  __syncthreads();
  for (int s = 128; s > 0; s >>= 1) {
    if (tid < s) red[tid] = fmaxf(red[tid], red[tid + s]);
    __syncthreads();
  }
  float mx = red[0];
  __syncthreads();
  float sum = 0.f;
  for (int i = tid; i < n; i += 256) sum += __expf(z[i] - mx);
  red[tid] = sum;
  __syncthreads();
  for (int s = 128; s > 0; s >>= 1) {
    if (tid < s) red[tid] += red[tid + s];
    __syncthreads();
  }
  float lse = mx + logf(red[0]);
  for (int i = tid; i < n; i += 256) out[i] = z[i] - lse;
}

extern "C" void kernel_launch(void* const* d_in, const int* in_sizes, int n_in,
                              void* d_out, int out_size, void* d_ws, size_t ws_size,
                              hipStream_t stream) {
  const float* game_x = (const float*)d_in[0];
  const float* state_x = (const float*)d_in[1];
  const float* pc_x = (const float*)d_in[2];
  const int* ei_vv = (const int*)d_in[3];
  const int* et_vv = (const int*)d_in[4];
  const int* ei_hist = (const int*)d_in[5];
  const float* ea_hist = (const float*)d_in[6];
  const int* ei_in = (const int*)d_in[7];
  const int* ei_ss = (const int*)d_in[8];
  const int* ei_pp = (const int*)d_in[9];
  const int* ei_ps = (const int*)d_in[10];
  const float* tag10_w = (const float*)d_in[12];
  const float* tag10_b = (const float*)d_in[13];
  const float* rgcn_w = (const float*)d_in[14];
  const float* rgcn_root = (const float*)d_in[15];
  const float* rgcn_b = (const float*)d_in[16];
  const float* gcn1_w = (const float*)d_in[17];
  const float* gcn1_b = (const float*)d_in[18];
  const float* gcn2_w = (const float*)d_in[19];
  const float* gcn2_b = (const float*)d_in[20];
  const float* rg_key_w = (const float*)d_in[21];
  const float* rg_key_b = (const float*)d_in[22];
  const float* rg_query_w = (const float*)d_in[23];
  const float* rg_query_b = (const float*)d_in[24];
  const float* rg_value_w = (const float*)d_in[25];
  const float* rg_value_b = (const float*)d_in[26];
  const float* rg_edge_w = (const float*)d_in[27];
  const float* rg_skip_w = (const float*)d_in[28];
  const float* rg_b = (const float*)d_in[29];
  const float* sage32_lw = (const float*)d_in[30];
  const float* sage32_lb = (const float*)d_in[31];
  const float* sage32_rw = (const float*)d_in[32];
  const float* sage4_lw = (const float*)d_in[33];
  const float* sage4_lb = (const float*)d_in[34];
  const float* sage4_rw = (const float*)d_in[35];
  const float* sage42_lw = (const float*)d_in[36];
  const float* sage42_lb = (const float*)d_in[37];
  const float* sage42_rw = (const float*)d_in[38];
  const float* pcs_lw = (const float*)d_in[39];
  const float* pcs_lb = (const float*)d_in[40];
  const float* pcs_rw = (const float*)d_in[41];
  const float* tag2_w = (const float*)d_in[42];
  const float* tag2_b = (const float*)d_in[43];
  const float* sage5_lw = (const float*)d_in[44];
  const float* sage5_lb = (const float*)d_in[45];
  const float* sage5_rw = (const float*)d_in[46];
  const float* lin_w = (const float*)d_in[47];
  const float* lin_b = (const float*)d_in[48];
  const float* linl_w = (const float*)d_in[49];
  const float* linl_b = (const float*)d_in[50];

  const int Evv = in_sizes[3] / 2, Eh = in_sizes[5] / 2, Ein = in_sizes[7] / 2,
            Ess = in_sizes[8] / 2, Epp = in_sizes[9] / 2, Eps = in_sizes[10] / 2;
  const int EE = Evv + Epp + Eh + Ein + Eps + Ess;
  const int NN = NG + NP + 4 * NS;

  // ---- workspace layout (bytes). Peak ~128 MB. ----
  char* base = (char*)d_ws;
  const size_t B_NGH = (size_t)NG * H * 2;
  const size_t B_NPH = (size_t)NP * H * 2;
  const size_t B_NSH = (size_t)NS * H * 2;
  unsigned short* g_tag_b = (unsigned short*)base;             // later q_b
  unsigned short* g_b = (unsigned short*)(base + B_NGH);
  char* C0 = base + 2 * B_NGH;
  uint2* tmp_pairs = (uint2*)C0;
  unsigned short* P_tag10_b = (unsigned short*)C0;
  unsigned short* G3_b = (unsigned short*)C0;
  unsigned short* xW_b = (unsigned short*)C0;
  unsigned short* p1b_b = (unsigned short*)(C0 + B_NPH);
  unsigned short* p2b_b = (unsigned short*)(C0 + 2 * B_NPH);
  unsigned short* v_b = (unsigned short*)C0;
  unsigned short* q_b = g_tag_b;
  unsigned short* P_tag2_b = (unsigned short*)C0;
  char* S0 = base + 2 * B_NGH + 46000000;
  unsigned short* S_a_b = (unsigned short*)S0;
  unsigned short* S_b_b = (unsigned short*)(S0 + B_NSH);
  unsigned short* m_buf_b = (unsigned short*)(S0 + 2 * B_NSH);
  unsigned short* kk_b = (unsigned short*)(S0 + 3 * B_NSH);
  float* Sfin = (float*)(S0 + 4 * B_NSH);
  unsigned short* Wt = (unsigned short*)(S0 + 4 * B_NSH + (size_t)NS * H * 4);
  int* ip = (int*)(S0 + 4 * B_NSH + (size_t)NS * H * 4 + 700000);
  int* rp_all = ip; ip += NN + 1;
  int* eidx_all = ip; ip += EE;
  int* table = ip; ip += 512 * 240;
  int* coarseOff = ip; ip += 520;
  int* colsum = ip; ip += 512;
  float* fp = (float*)ip;
  float* dinv_all = fp; fp += NN;
  float* z = fp; fp += NS;
  unsigned char* g_tag_8 = (unsigned char*)(z + NS);        // NG*128 B
  unsigned char* qvg_8 = g_tag_8 + (size_t)NG * H;          // NG*384 B interleaved q|v|g

  // graph order: 0=vv, 1=pp, 2=hh, 3=in, 4=ps, 5=ss
  Seg6 sg;
  sg.col[0] = ei_vv + Evv;  sg.row[0] = ei_vv;
  sg.col[1] = ei_pp + Epp;  sg.row[1] = ei_pp;
  sg.col[2] = ei_hist + Eh; sg.row[2] = ei_hist;
  sg.col[3] = ei_in + Ein;  sg.row[3] = ei_in;
  sg.col[4] = ei_ps + Eps;  sg.row[4] = ei_ps;
  sg.col[5] = ei_ss + Ess;  sg.row[5] = ei_ss;
  sg.et0 = et_vv;
  int no[7] = {0, NG, NG + NP, NG + NP + NS, NG + NP + 2 * NS, NG + NP + 3 * NS, NN};
  int eo[7] = {0, Evv, Evv + Epp, Evv + Epp + Eh, Evv + Epp + Eh + Ein,
               Evv + Epp + Eh + Ein + Eps, EE};
  for (int i = 0; i < 7; i++) { sg.nodeoff[i] = no[i]; sg.edgeoff[i] = eo[i]; }
  int md[6] = {1, 0, 2, 0, 0, 0};
  float as[6] = {0.f, 1.f, 0.f, 0.f, 0.f, 0.f};
  int hd[6] = {1, 1, 0, 0, 0, 1};
  for (int i = 0; i < 6; i++) { sg.mode[i] = md[i]; sg.addself[i] = as[i]; sg.hasdinv[i] = hd[i]; }

  const int* rp_vv = rp_all + no[0];
  const int* rp_pp = rp_all + no[1];
  const int* rp_hh = rp_all + no[2];
  const int* rp_in = rp_all + no[3];
  const int* rp_ps = rp_all + no[4];
  const int* rp_ss = rp_all + no[5];
  const float* dinvG = dinv_all + no[0];
  const float* dinvP = dinv_all + no[1];
  const float* dinvS = dinv_all + no[5];
  const int* rh = ei_hist;

  // ---- weight pre-pack (transposed bf16) ----
  Pack17 pk;
  const float* wsrc[17] = {tag10_w, rgcn_w, rgcn_root, gcn2_w, rg_query_w, rg_value_w,
                           sage32_lw, sage32_rw, sage4_lw, sage4_rw, sage42_lw, sage42_rw,
                           pcs_lw, pcs_rw, tag2_w, sage5_lw, sage5_rw};
  int ksrc[17] = {28, 384, 128, 128, 128, 128, 128, 128, 128, 128, 128, 128, 128, 128, 384, 128, 128};
  int kdst[17] = {32, 384, 128, 128, 128, 128, 128, 128, 128, 128, 128, 128, 128, 128, 384, 128, 128};
  int run = 0;
  for (int i = 0; i < 17; i++) {
    pk.d[i].src = wsrc[i]; pk.d[i].Ksrc = ksrc[i]; pk.d[i].Kdst = kdst[i];
    pk.koff[i] = run; run += kdst[i];
  }
  pk.koff[17] = run;
  unsigned short* WT[17];
  for (int i = 0; i < 17; i++) WT[i] = Wt + (size_t)pk.koff[i] * 128;
  k_pack<<<nblk((long long)run * 128), 256, 0, stream>>>(pk, Wt, run);

  // ---- atomic-free CSR build (6 dispatches, fully parallel scan) ----
  int nblkA = (EE + CSR_CHUNK - 1) / CSR_CHUNK;
  int B = (NN + 511) / 512;
  k_hist<<<nblkA, 256, 0, stream>>>(sg, EE, table);
  k_scanT1<<<512, 256, 0, stream>>>(table, nblkA, colsum);
  k_scanT2<<<1, 512, 0, stream>>>(colsum, coarseOff);
  k_scanT3<<<nblk((long long)nblkA * 512), 256, 0, stream>>>(table, coarseOff, nblkA * 512);
  k_scatterA<<<nblkA, 256, 0, stream>>>(sg, EE, table, tmp_pairs);
  k_localCSR<<<B, 256, 0, stream>>>(tmp_pairs, coarseOff, sg, NN, EE, B,
                                    rp_all, eidx_all, dinv_all);

  // ================= phase 1: TAGConv game =================
  k_copy7b<<<nblk((long long)NG * 32), 256, 0, stream>>>(game_x, P_tag10_b, NG);
  k_gnorm7w<<<(NG + 3) / 4, 256, 0, stream>>>(P_tag10_b, 32, 0, eidx_all, rp_vv, dinvG,
                                              P_tag10_b, 32, 7, NG);
  k_gnorm7w<<<(NG + 3) / 4, 256, 0, stream>>>(P_tag10_b, 32, 7, eidx_all, rp_vv, dinvG,
                                              P_tag10_b, 32, 14, NG);
  k_gnorm7w<<<(NG + 3) / 4, 256, 0, stream>>>(P_tag10_b, 32, 14, eidx_all, rp_vv, dinvG,
                                              P_tag10_b, 32, 21, NG);
  k_mgemm<<<mgb(NG), 256, 0, stream>>>(P_tag10_b, 32, 32, WT[0], nullptr, 0, 0, nullptr,
                                       tag10_b, g_tag_b, H, NG, TG_RELU | TG_OUTBF16,
                                       g_tag_8, H);

  // ================= phase 2: RGCN (fp8 rel-gather + dual-K GEMM) =================
  k_grel3<<<(NG + 3) / 4, 256, 0, stream>>>(g_tag_8, eidx_all, rp_vv, G3_b, NG);
  k_mgemm<<<mgb(NG), 256, 0, stream>>>(G3_b, 384, 384, WT[1], g_tag_b, H, H, WT[2],
                                       rgcn_b, g_b, H, NG, TG_RELU | TG_OUTBF16,
                                       qvg_8 + 256, 384);

  // ================= phase 3: pc graph (2x GCN) =================
  k_gemm128b<<<nblk((long long)NP * H), 256, 0, stream>>>(pc_x, gcn1_w, nullptr, xW_b, NP, 5);
  k_gnorm<<<(NP + 3) / 4, 256, 0, stream>>>(xW_b, H, 0, eidx_all, rp_pp, dinvP, xW_b, gcn1_b,
                                            p1b_b, H, 0, 1, NP);
  k_mgemm<<<mgb(NP), 256, 0, stream>>>(p1b_b, H, H, WT[3], nullptr, 0, 0, nullptr,
                                       nullptr, xW_b, H, NP, TG_OUTBF16, nullptr, 0);
  k_gnorm<<<(NP + 3) / 4, 256, 0, stream>>>(xW_b, H, 0, eidx_all, rp_pp, dinvP, xW_b, gcn2_b,
                                            p2b_b, H, 0, 1, NP);

  // ================= phase 4: ResGated + hh-mean (fused, interleaved fp8 qvg) =======
  k_gemm128b<<<nblk((long long)NS * H), 256, 0, stream>>>(state_x, rg_key_w, rg_key_b, kk_b, NS, 6);
  k_mgemm<<<mgb(NG), 256, 0, stream>>>(g_b, H, H, WT[4], nullptr, 0, 0, nullptr,
                                       rg_query_b, q_b, H, NG, TG_OUTBF16, qvg_8, 384);
  k_mgemm<<<mgb(NG), 256, 0, stream>>>(g_b, H, H, WT[5], nullptr, 0, 0, nullptr,
                                       rg_value_b, v_b, H, NG, TG_OUTBF16, qvg_8 + 128, 384);
  k_resgated_mean<<<(NS + 3) / 4, 256, 0, stream>>>(kk_b, qvg_8, ea_hist, rg_edge_w, rh,
                                                    eidx_all, rp_hh, state_x, rg_skip_w, rg_b,
                                                    S_a_b, m_buf_b, NS);

  // ================= phase 5: sage32 =================
  k_mgemm<<<mgb(NS), 256, 0, stream>>>(m_buf_b, H, H, WT[6], S_a_b, H, H, WT[7],
                                       sage32_lb, S_b_b, H, NS, TG_NORM | TG_OUTBF16, nullptr, 0);

  // ================= phase 6: sage4 + sage42 (in, shared fp8 mean of g plane) =======
  k_gmean_f8<<<(NS + 3) / 4, 256, 0, stream>>>(qvg_8, 384, 256, eidx_all, rp_in, m_buf_b, NS);
  k_mgemm<<<mgb(NS), 256, 0, stream>>>(m_buf_b, H, H, WT[8], S_b_b, H, H, WT[9],
                                       sage4_lb, S_a_b, H, NS, TG_NORM | TG_OUTBF16, nullptr, 0);
  k_mgemm<<<mgb(NS), 256, 0, stream>>>(m_buf_b, H, H, WT[10], S_a_b, H, H, WT[11],
                                       sage42_lb, S_b_b, H, NS, TG_NORM | TG_OUTBF16, nullptr, 0);

  // ================= phase 7: pcs sage =================
  k_gmean<<<(NS + 3) / 4, 256, 0, stream>>>(p2b_b, eidx_all, rp_ps, m_buf_b, NS);
  k_mgemm<<<mgb(NS), 256, 0, stream>>>(m_buf_b, H, H, WT[12], S_b_b, H, H, WT[13],
                                       pcs_lb, P_tag2_b, 384, NS, TG_NORM | TG_OUTBF16, nullptr, 0);

  // ================= phase 8: tag2 =================
  k_gnorm<<<(NS + 3) / 4, 256, 0, stream>>>(P_tag2_b, 384, 0, eidx_all, rp_ss, dinvS, nullptr,
                                            nullptr, P_tag2_b, 384, 128, 0, NS);
  k_gnorm<<<(NS + 3) / 4, 256, 0, stream>>>(P_tag2_b, 384, 128, eidx_all, rp_ss, dinvS, nullptr,
                                            nullptr, P_tag2_b, 384, 256, 0, NS);
  k_mgemm<<<mgb(NS), 256, 0, stream>>>(P_tag2_b, 384, 384, WT[14], nullptr, 0, 0, nullptr,
                                       tag2_b, S_b_b, H, NS, TG_RELU | TG_OUTBF16, nullptr, 0);

  // ================= phase 9: sage5 =================
  k_gmean<<<(NS + 3) / 4, 256, 0, stream>>>(S_b_b, eidx_all, rp_ss, m_buf_b, NS);
  k_mgemm<<<mgb(NS), 256, 0, stream>>>(m_buf_b, H, H, WT[15], S_b_b, H, H, WT[16],
                                       sage5_lb, Sfin, H, NS, TG_NORM, nullptr, 0);

  // ================= head =================
  k_head<<<(NS + 7) / 8, 256, 0, stream>>>(Sfin, lin_w, lin_b, linl_w, linl_b, z, NS);
  k_logsoftmax<<<1, 256, 0, stream>>>(z, (float*)d_out, NS);
}

// Round 13
// 665.313 us; speedup vs baseline: 1.0759x; 1.0759x over previous
//
#include <hip/hip_runtime.h>
#include <cstdint>

#define H 128
static const int NG = 50000, NS = 20000, NP = 30000;

#define TG_RELU 2
#define TG_NORM 4
#define TG_OUTBF16 8

#define CSR_CHUNK 2048

typedef __attribute__((ext_vector_type(8))) short bf16x8;
typedef __attribute__((ext_vector_type(4))) float f32x4;
typedef __attribute__((ext_vector_type(2))) float v2f;

static inline int nblk(long long n) { return (int)((n + 255) / 256); }

__device__ inline unsigned short f2b(float f) {
  unsigned int u = __float_as_uint(f);
  u += 0x7FFFu + ((u >> 16) & 1u);
  return (unsigned short)(u >> 16);
}
__device__ inline float b2f(unsigned short u) {
  return __uint_as_float(((unsigned int)u) << 16);
}
__device__ inline float2 bfp2(unsigned int u) {
  return make_float2(__uint_as_float(u << 16), __uint_as_float(u & 0xFFFF0000u));
}
__device__ inline unsigned int f2bfp(float x, float y) {
  return ((unsigned int)f2b(y) << 16) | (unsigned int)f2b(x);
}
// fp8 e4m3 (OCP) hw-converters
__device__ inline float2 f8p2(unsigned short u) {
  v2f r = __builtin_amdgcn_cvt_pk_f32_fp8((int)(unsigned int)u, false);
  return make_float2(r.x, r.y);
}
__device__ inline unsigned char f2f8(float x) {
  int r = __builtin_amdgcn_cvt_pk_fp8_f32(x, 0.f, 0, false);
  return (unsigned char)(r & 0xFF);
}

// ================= atomic-free batched CSR build =================
struct Seg6 {
  const int* col[6];
  const int* row[6];
  const int* et0;
  int nodeoff[7];
  int edgeoff[7];
  int mode[6];         // 0=row, 1=row|(et<<16), 2=edge id (local)
  float addself[6];
  int hasdinv[6];
};

__global__ __launch_bounds__(256) void k_hist(Seg6 sg, int EE, int* __restrict__ table) {
  __shared__ int h[512];
  int tid = threadIdx.x, blk = blockIdx.x;
  h[tid] = 0; h[tid + 256] = 0;
  __syncthreads();
  int e0 = blk * CSR_CHUNK, e1 = min(EE, e0 + CSR_CHUNK);
  for (int e = e0 + tid; e < e1; e += 256) {
    int gi = 0;
    while (e >= sg.edgeoff[gi + 1]) gi++;
    int le = e - sg.edgeoff[gi];
    int gn = sg.nodeoff[gi] + sg.col[gi][le];
    atomicAdd(&h[gn >> 9], 1);  // LDS atomic
  }
  __syncthreads();
  table[blk * 512 + tid] = h[tid];
  table[blk * 512 + tid + 256] = h[tid + 256];
}

// per-bucket-column exclusive scan; handles nblkA <= 1024 (4 rows per thread)
__global__ __launch_bounds__(256) void k_scanT1(int* __restrict__ table, int nblkA,
                                                int* __restrict__ colsum) {
  __shared__ int s[256];
  int b = blockIdx.x;
  int t = threadIdx.x;
  int v[4];
  int loc = 0;
#pragma unroll
  for (int i = 0; i < 4; i++) {
    int r = t * 4 + i;
    v[i] = (r < nblkA) ? table[r * 512 + b] : 0;
    loc += v[i];
  }
  s[t] = loc;
  __syncthreads();
  for (int off = 1; off < 256; off <<= 1) {
    int x = s[t];
    int u = (t >= off) ? s[t - off] : 0;
    __syncthreads();
    s[t] = x + u;
    __syncthreads();
  }
  int excl = (t > 0) ? s[t - 1] : 0;
#pragma unroll
  for (int i = 0; i < 4; i++) {
    int r = t * 4 + i;
    if (r < nblkA) table[r * 512 + b] = excl;
    excl += v[i];
  }
  if (t == 255) colsum[b] = s[255];
}

__global__ void k_scanT2(const int* __restrict__ colsum, int* __restrict__ coarseOff) {
  __shared__ int cs[512];
  int b = threadIdx.x;
  cs[b] = colsum[b];
  __syncthreads();
  for (int off = 1; off < 512; off <<= 1) {
    int v = cs[b];
    int u = (b >= off) ? cs[b - off] : 0;
    __syncthreads();
    cs[b] = v + u;
    __syncthreads();
  }
  coarseOff[b] = (b > 0) ? cs[b - 1] : 0;
  if (b == 511) coarseOff[512] = cs[511];
}

__global__ void k_scanT3(int* __restrict__ table, const int* __restrict__ coarseOff, int n) {
  int i = blockIdx.x * blockDim.x + threadIdx.x;
  if (i < n) table[i] += coarseOff[i & 511];
}

__global__ __launch_bounds__(256) void k_scatterA(Seg6 sg, int EE, const int* __restrict__ table,
                                                  uint2* __restrict__ tmp) {
  __shared__ int cur[512];
  int tid = threadIdx.x, blk = blockIdx.x;
  cur[tid] = table[blk * 512 + tid];
  cur[tid + 256] = table[blk * 512 + tid + 256];
  __syncthreads();
  int e0 = blk * CSR_CHUNK, e1 = min(EE, e0 + CSR_CHUNK);
  for (int e = e0 + tid; e < e1; e += 256) {
    int gi = 0;
    while (e >= sg.edgeoff[gi + 1]) gi++;
    int le = e - sg.edgeoff[gi];
    int gn = sg.nodeoff[gi] + sg.col[gi][le];
    int m = sg.mode[gi];
    int pay;
    if (m == 2) pay = le;
    else {
      pay = sg.row[gi][le];
      if (m == 1) pay |= sg.et0[le] << 16;
    }
    int pos = atomicAdd(&cur[gn >> 9], 1);
    tmp[pos] = make_uint2((unsigned)gn, (unsigned)pay);
  }
}

__global__ __launch_bounds__(256) void k_localCSR(const uint2* __restrict__ tmp,
                                                  const int* __restrict__ coarseOff,
                                                  Seg6 sg, int NN, int EE, int B,
                                                  int* __restrict__ rowptr,
                                                  int* __restrict__ eidx,
                                                  float* __restrict__ dinv) {
  int b = blockIdx.x, tid = threadIdx.x;
  int base = b * 512;
  int nNodes = min(512, NN - base);
  int beg = coarseOff[b], end = coarseOff[b + 1];
  __shared__ int cnt[512];
  __shared__ int off[512];
  __shared__ int ps[256];
  cnt[tid] = 0; cnt[tid + 256] = 0;
  __syncthreads();
  for (int j = beg + tid; j < end; j += 256)
    atomicAdd(&cnt[tmp[j].x - base], 1);
  __syncthreads();
  int a = cnt[2 * tid], bb = cnt[2 * tid + 1];
  ps[tid] = a + bb;
  __syncthreads();
  for (int o = 1; o < 256; o <<= 1) {
    int v = ps[tid];
    int u = (tid >= o) ? ps[tid - o] : 0;
    __syncthreads();
    ps[tid] = v + u;
    __syncthreads();
  }
  int excl = (tid > 0) ? ps[tid - 1] : 0;
  off[2 * tid] = excl;
  off[2 * tid + 1] = excl + a;
  __syncthreads();
  for (int i = tid; i < nNodes; i += 256) {
    int gid = base + i;
    rowptr[gid] = beg + off[i];
    int gi = 0;
    while (gid >= sg.nodeoff[gi + 1]) gi++;
    if (sg.hasdinv[gi]) {
      float d = (float)cnt[i] + sg.addself[gi];
      dinv[gid] = (d > 0.f) ? rsqrtf(d) : 0.f;
    }
  }
  if (b == B - 1 && tid == 0) rowptr[NN] = EE;
  __syncthreads();
  for (int j = beg + tid; j < end; j += 256) {
    uint2 p = tmp[j];
    int pos = beg + atomicAdd(&off[p.x - base], 1);
    eidx[pos] = (int)p.y;
  }
}

// ================= weight pre-pack =================
struct PackD { const float* src; int Ksrc; int Kdst; };
struct Pack17 { PackD d[17]; int koff[18]; };

__global__ void k_pack(Pack17 p, unsigned short* __restrict__ Wt, int totalRows) {
  int t = blockIdx.x * blockDim.x + threadIdx.x;
  if (t >= totalRows * 128) return;
  int gk = t >> 7, n = t & 127;
  int w = 0;
  while (gk >= p.koff[w + 1]) w++;
  int k = gk - p.koff[w];
  float v = (k < p.d[w].Ksrc) ? p.d[w].src[(size_t)k * 128 + n] : 0.f;
  Wt[(size_t)p.koff[w] * 128 + (size_t)n * p.d[w].Kdst + k] = f2b(v);
}

// ================= wave-per-node gathers (no LDS, no syncs) =================
// bf16-source mean
__global__ __launch_bounds__(256) void k_gmean(const unsigned short* __restrict__ src,
                                               const int* __restrict__ eidx,
                                               const int* __restrict__ rowptr,
                                               unsigned short* __restrict__ out, int N) {
  int c = blockIdx.x * 4 + (threadIdx.x >> 6);
  if (c >= N) return;
  int lane = threadIdx.x & 63;
  int beg = rowptr[c], end = rowptr[c + 1];
  float2 A0 = {0.f, 0.f}, A1 = {0.f, 0.f}, A2 = {0.f, 0.f}, A3 = {0.f, 0.f};
  int j = beg;
  for (; j + 4 <= end; j += 4) {
    int e0 = eidx[j], e1 = eidx[j + 1], e2 = eidx[j + 2], e3 = eidx[j + 3];
    float2 v0 = bfp2(*(const unsigned int*)(src + (size_t)e0 * H + lane * 2));
    float2 v1 = bfp2(*(const unsigned int*)(src + (size_t)e1 * H + lane * 2));
    float2 v2 = bfp2(*(const unsigned int*)(src + (size_t)e2 * H + lane * 2));
    float2 v3 = bfp2(*(const unsigned int*)(src + (size_t)e3 * H + lane * 2));
    A0.x += v0.x; A0.y += v0.y;
    A1.x += v1.x; A1.y += v1.y;
    A2.x += v2.x; A2.y += v2.y;
    A3.x += v3.x; A3.y += v3.y;
  }
  for (; j < end; j++) {
    float2 v = bfp2(*(const unsigned int*)(src + (size_t)eidx[j] * H + lane * 2));
    A0.x += v.x; A0.y += v.y;
  }
  int cnt = end - beg;
  float s = 1.f / (float)(cnt > 0 ? cnt : 1);
  float ox = (A0.x + A1.x + A2.x + A3.x) * s;
  float oy = (A0.y + A1.y + A2.y + A3.y) * s;
  *(unsigned int*)(out + (size_t)c * H + lane * 2) = f2bfp(ox, oy);
}

// fp8-source mean (strided source)
__global__ __launch_bounds__(256) void k_gmean_f8(const unsigned char* __restrict__ src,
                                                  long ldS, int offS,
                                                  const int* __restrict__ eidx,
                                                  const int* __restrict__ rowptr,
                                                  unsigned short* __restrict__ out, int N) {
  int c = blockIdx.x * 4 + (threadIdx.x >> 6);
  if (c >= N) return;
  int lane = threadIdx.x & 63;
  int beg = rowptr[c], end = rowptr[c + 1];
  float2 A0 = {0.f, 0.f}, A1 = {0.f, 0.f}, A2 = {0.f, 0.f}, A3 = {0.f, 0.f};
  int j = beg;
  for (; j + 4 <= end; j += 4) {
    int e0 = eidx[j], e1 = eidx[j + 1], e2 = eidx[j + 2], e3 = eidx[j + 3];
    float2 v0 = f8p2(*(const unsigned short*)(src + (size_t)e0 * ldS + offS + lane * 2));
    float2 v1 = f8p2(*(const unsigned short*)(src + (size_t)e1 * ldS + offS + lane * 2));
    float2 v2 = f8p2(*(const unsigned short*)(src + (size_t)e2 * ldS + offS + lane * 2));
    float2 v3 = f8p2(*(const unsigned short*)(src + (size_t)e3 * ldS + offS + lane * 2));
    A0.x += v0.x; A0.y += v0.y;
    A1.x += v1.x; A1.y += v1.y;
    A2.x += v2.x; A2.y += v2.y;
    A3.x += v3.x; A3.y += v3.y;
  }
  for (; j < end; j++) {
    float2 v = f8p2(*(const unsigned short*)(src + (size_t)eidx[j] * ldS + offS + lane * 2));
    A0.x += v.x; A0.y += v.y;
  }
  int cnt = end - beg;
  float s = 1.f / (float)(cnt > 0 ? cnt : 1);
  float ox = (A0.x + A1.x + A2.x + A3.x) * s;
  float oy = (A0.y + A1.y + A2.y + A3.y) * s;
  *(unsigned int*)(out + (size_t)c * H + lane * 2) = f2bfp(ox, oy);
}

// 3-relation mean (fp8 source, 4-unrolled) -> concatenated 384-wide bf16 row
__global__ __launch_bounds__(256) void k_grel3(const unsigned char* __restrict__ src,
                                               const int* __restrict__ eidx,
                                               const int* __restrict__ rowptr,
                                               unsigned short* __restrict__ G3, int N) {
  int c = blockIdx.x * 4 + (threadIdx.x >> 6);
  if (c >= N) return;
  int lane = threadIdx.x & 63;
  int beg = rowptr[c], end = rowptr[c + 1];
  float2 a0 = {0.f, 0.f}, a1 = {0.f, 0.f}, a2 = {0.f, 0.f};
  int c0 = 0, c1 = 0, c2 = 0;
  int j = beg;
  for (; j + 4 <= end; j += 4) {
    int p0 = eidx[j], p1 = eidx[j + 1], p2 = eidx[j + 2], p3 = eidx[j + 3];
    float2 w0 = f8p2(*(const unsigned short*)(src + (size_t)(p0 & 0xFFFF) * H + lane * 2));
    float2 w1 = f8p2(*(const unsigned short*)(src + (size_t)(p1 & 0xFFFF) * H + lane * 2));
    float2 w2 = f8p2(*(const unsigned short*)(src + (size_t)(p2 & 0xFFFF) * H + lane * 2));
    float2 w3 = f8p2(*(const unsigned short*)(src + (size_t)(p3 & 0xFFFF) * H + lane * 2));
    int r0 = p0 >> 16, r1 = p1 >> 16, r2 = p2 >> 16, r3 = p3 >> 16;
    if (r0 == 0) { a0.x += w0.x; a0.y += w0.y; c0++; }
    else if (r0 == 1) { a1.x += w0.x; a1.y += w0.y; c1++; }
    else { a2.x += w0.x; a2.y += w0.y; c2++; }
    if (r1 == 0) { a0.x += w1.x; a0.y += w1.y; c0++; }
    else if (r1 == 1) { a1.x += w1.x; a1.y += w1.y; c1++; }
    else { a2.x += w1.x; a2.y += w1.y; c2++; }
    if (r2 == 0) { a0.x += w2.x; a0.y += w2.y; c0++; }
    else if (r2 == 1) { a1.x += w2.x; a1.y += w2.y; c1++; }
    else { a2.x += w2.x; a2.y += w2.y; c2++; }
    if (r3 == 0) { a0.x += w3.x; a0.y += w3.y; c0++; }
    else if (r3 == 1) { a1.x += w3.x; a1.y += w3.y; c1++; }
    else { a2.x += w3.x; a2.y += w3.y; c2++; }
  }
  for (; j < end; j++) {
    int pk = eidx[j];
    int rel = pk >> 16;
    float2 v = f8p2(*(const unsigned short*)(src + (size_t)(pk & 0xFFFF) * H + lane * 2));
    if (rel == 0) { a0.x += v.x; a0.y += v.y; c0++; }
    else if (rel == 1) { a1.x += v.x; a1.y += v.y; c1++; }
    else { a2.x += v.x; a2.y += v.y; c2++; }
  }
  float s0 = 1.f / (float)(c0 > 0 ? c0 : 1);
  float s1 = 1.f / (float)(c1 > 0 ? c1 : 1);
  float s2 = 1.f / (float)(c2 > 0 ? c2 : 1);
  size_t base = (size_t)c * 384 + lane * 2;
  *(unsigned int*)(G3 + base) = f2bfp(a0.x * s0, a0.y * s0);
  *(unsigned int*)(G3 + base + 128) = f2bfp(a1.x * s1, a1.y * s1);
  *(unsigned int*)(G3 + base + 256) = f2bfp(a2.x * s2, a2.y * s2);
}

// symmetric-normalized gather (+ optional self + bias + relu), strided bf16
__global__ __launch_bounds__(256) void k_gnorm(const unsigned short* __restrict__ src,
                                               long ldS, int offS,
                                               const int* __restrict__ eidx,
                                               const int* __restrict__ rowptr,
                                               const float* __restrict__ dinv,
                                               const unsigned short* __restrict__ selfX,
                                               const float* __restrict__ bias,
                                               unsigned short* __restrict__ out,
                                               long ldD, int offD, int relu, int N) {
  int c = blockIdx.x * 4 + (threadIdx.x >> 6);
  if (c >= N) return;
  int lane = threadIdx.x & 63;
  int beg = rowptr[c], end = rowptr[c + 1];
  float2 A0 = {0.f, 0.f}, A1 = {0.f, 0.f}, A2 = {0.f, 0.f}, A3 = {0.f, 0.f};
  int j = beg;
  for (; j + 4 <= end; j += 4) {
    int e0 = eidx[j], e1 = eidx[j + 1], e2 = eidx[j + 2], e3 = eidx[j + 3];
    float w0 = dinv[e0], w1 = dinv[e1], w2 = dinv[e2], w3 = dinv[e3];
    float2 v0 = bfp2(*(const unsigned int*)(src + (size_t)e0 * ldS + offS + lane * 2));
    float2 v1 = bfp2(*(const unsigned int*)(src + (size_t)e1 * ldS + offS + lane * 2));
    float2 v2 = bfp2(*(const unsigned int*)(src + (size_t)e2 * ldS + offS + lane * 2));
    float2 v3 = bfp2(*(const unsigned int*)(src + (size_t)e3 * ldS + offS + lane * 2));
    A0.x = fmaf(w0, v0.x, A0.x); A0.y = fmaf(w0, v0.y, A0.y);
    A1.x = fmaf(w1, v1.x, A1.x); A1.y = fmaf(w1, v1.y, A1.y);
    A2.x = fmaf(w2, v2.x, A2.x); A2.y = fmaf(w2, v2.y, A2.y);
    A3.x = fmaf(w3, v3.x, A3.x); A3.y = fmaf(w3, v3.y, A3.y);
  }
  for (; j < end; j++) {
    int e = eidx[j];
    float w = dinv[e];
    float2 v = bfp2(*(const unsigned int*)(src + (size_t)e * ldS + offS + lane * 2));
    A0.x = fmaf(w, v.x, A0.x); A0.y = fmaf(w, v.y, A0.y);
  }
  float dc = dinv[c];
  float ox = (A0.x + A1.x + A2.x + A3.x) * dc;
  float oy = (A0.y + A1.y + A2.y + A3.y) * dc;
  if (selfX) {
    float2 sv = bfp2(*(const unsigned int*)(selfX + (size_t)c * H + lane * 2));
    ox += dc * dc * sv.x;
    oy += dc * dc * sv.y;
  }
  if (bias) {
    float2 bv = *(const float2*)(bias + lane * 2);
    ox += bv.x; oy += bv.y;
  }
  if (relu) { ox = fmaxf(ox, 0.f); oy = fmaxf(oy, 0.f); }
  *(unsigned int*)(out + (size_t)c * ldD + offD + lane * 2) = f2bfp(ox, oy);
}

// fused ResGated + hh-mean: interleaved fp8 qvg rows (q@0, v@128, g@256; ld=384)
__global__ __launch_bounds__(256) void k_resgated_mean(const unsigned short* __restrict__ kk,
                                                       const unsigned char* __restrict__ qvg,
                                                       const float* __restrict__ ea,
                                                       const float* __restrict__ We,
                                                       const int* __restrict__ rh,
                                                       const int* __restrict__ eidx,
                                                       const int* __restrict__ rowptr,
                                                       const float* __restrict__ sx,
                                                       const float* __restrict__ Wsk,
                                                       const float* __restrict__ rgb,
                                                       unsigned short* __restrict__ outS,
                                                       unsigned short* __restrict__ outM, int N) {
  int c = blockIdx.x * 4 + (threadIdx.x >> 6);
  if (c >= N) return;
  int lane = threadIdx.x & 63;
  int d0 = lane * 2;
  int beg = rowptr[c], end = rowptr[c + 1];
  float2 kload = bfp2(*(const unsigned int*)(kk + (size_t)c * H + d0));
  float2 we0 = make_float2(We[d0], We[d0 + 1]);
  float2 we1 = make_float2(We[H + d0], We[H + d0 + 1]);
  float2 accS = {0.f, 0.f}, accM = {0.f, 0.f};
  int j = beg;
  for (; j + 4 <= end; j += 4) {
    int e0 = eidx[j], e1 = eidx[j + 1], e2 = eidx[j + 2], e3 = eidx[j + 3];
    int r0 = rh[e0], r1 = rh[e1], r2 = rh[e2], r3 = rh[e3];
    float2 ea0 = *(const float2*)(ea + 2 * e0);
    float2 ea1 = *(const float2*)(ea + 2 * e1);
    float2 ea2 = *(const float2*)(ea + 2 * e2);
    float2 ea3 = *(const float2*)(ea + 2 * e3);
    const unsigned char* b0 = qvg + (size_t)r0 * 384 + d0;
    const unsigned char* b1 = qvg + (size_t)r1 * 384 + d0;
    const unsigned char* b2 = qvg + (size_t)r2 * 384 + d0;
    const unsigned char* b3 = qvg + (size_t)r3 * 384 + d0;
    unsigned short uq0 = *(const unsigned short*)(b0);
    unsigned short uv0 = *(const unsigned short*)(b0 + 128);
    unsigned short ug0 = *(const unsigned short*)(b0 + 256);
    unsigned short uq1 = *(const unsigned short*)(b1);
    unsigned short uv1 = *(const unsigned short*)(b1 + 128);
    unsigned short ug1 = *(const unsigned short*)(b1 + 256);
    unsigned short uq2 = *(const unsigned short*)(b2);
    unsigned short uv2 = *(const unsigned short*)(b2 + 128);
    unsigned short ug2 = *(const unsigned short*)(b2 + 256);
    unsigned short uq3 = *(const unsigned short*)(b3);
    unsigned short uv3 = *(const unsigned short*)(b3 + 128);
    unsigned short ug3 = *(const unsigned short*)(b3 + 256);
#define RG_STEP(UQ, UV, UG, EA)                                            \
    {                                                                      \
      float2 qv = f8p2(UQ);                                                \
      float2 vv = f8p2(UV);                                                \
      float2 gv = f8p2(UG);                                                \
      float x0 = kload.x + qv.x + (EA).x * we0.x + (EA).y * we1.x;         \
      float x1 = kload.y + qv.y + (EA).x * we0.y + (EA).y * we1.y;         \
      float eta0 = 1.f / (1.f + __expf(-x0));                              \
      float eta1 = 1.f / (1.f + __expf(-x1));                              \
      accS.x = fmaf(eta0, vv.x, accS.x);                                   \
      accS.y = fmaf(eta1, vv.y, accS.y);                                   \
      accM.x += gv.x; accM.y += gv.y;                                      \
    }
    RG_STEP(uq0, uv0, ug0, ea0)
    RG_STEP(uq1, uv1, ug1, ea1)
    RG_STEP(uq2, uv2, ug2, ea2)
    RG_STEP(uq3, uv3, ug3, ea3)
  }
  for (; j < end; j++) {
    int e = eidx[j];
    int r = rh[e];
    float2 eav = *(const float2*)(ea + 2 * e);
    const unsigned char* bp = qvg + (size_t)r * 384 + d0;
    unsigned short uq = *(const unsigned short*)(bp);
    unsigned short uv = *(const unsigned short*)(bp + 128);
    unsigned short ug = *(const unsigned short*)(bp + 256);
    RG_STEP(uq, uv, ug, eav)
  }
#undef RG_STEP
  float sk0 = rgb[d0], sk1 = rgb[d0 + 1];
#pragma unroll
  for (int f = 0; f < 6; f++) {
    float xf = sx[c * 6 + f];
    sk0 = fmaf(xf, Wsk[f * H + d0], sk0);
    sk1 = fmaf(xf, Wsk[f * H + d0 + 1], sk1);
  }
  *(unsigned int*)(outS + (size_t)c * H + d0) =
      f2bfp(fmaxf(accS.x + sk0, 0.f), fmaxf(accS.y + sk1, 0.f));
  int cnt = end - beg;
  float s = 1.f / (float)(cnt > 0 ? cnt : 1);
  *(unsigned int*)(outM + (size_t)c * H + d0) = f2bfp(accM.x * s, accM.y * s);
}

// 7-dim symmetric-normalized gather, wave-per-node: 64 lanes = 8 edge-groups x 8 features
__global__ __launch_bounds__(256) void k_gnorm7w(const unsigned short* __restrict__ src,
                                                 int ldS, int offS,
                                                 const int* __restrict__ eidx,
                                                 const int* __restrict__ rowptr,
                                                 const float* __restrict__ dinv,
                                                 unsigned short* __restrict__ dst,
                                                 int ldD, int offD, int N) {
  int c = blockIdx.x * 4 + (threadIdx.x >> 6);
  if (c >= N) return;
  int lane = threadIdx.x & 63;
  int eg = lane >> 3, f = lane & 7;
  int beg = rowptr[c], end = rowptr[c + 1];
  float acc = 0.f;
  for (int j = beg + eg; j < end; j += 8) {
    int r = eidx[j] & 0xFFFF;
    float w = dinv[r];
    float val = (f < 7) ? b2f(src[(size_t)r * ldS + offS + f]) : 0.f;
    acc = fmaf(w, val, acc);
  }
  acc += __shfl_xor(acc, 8);
  acc += __shfl_xor(acc, 16);
  acc += __shfl_xor(acc, 32);
  if (eg == 0 && f < 7)
    dst[(size_t)c * ldD + offD + f] = f2b(acc * dinv[c]);
}

// ================= small utilities =================
__global__ void k_copy7b(const float* __restrict__ src, unsigned short* __restrict__ dst, int n) {
  long long t = (long long)blockIdx.x * blockDim.x + threadIdx.x;
  int i = (int)(t >> 5), f = (int)(t & 31);
  if (i < n) dst[(size_t)i * 32 + f] = (f < 7) ? f2b(src[(size_t)i * 7 + f]) : 0;
}

__global__ void k_gemm128b(const float* __restrict__ X, const float* __restrict__ W,
                           const float* __restrict__ b, unsigned short* __restrict__ out,
                           int M, int K) {
  long long t = (long long)blockIdx.x * blockDim.x + threadIdx.x;
  if (t >= (long long)M * H) return;
  int i = (int)(t >> 7), h = (int)(t & 127);
  float acc = b ? b[h] : 0.f;
  const float* x = X + (long long)i * K;
  for (int k = 0; k < K; k++) acc = fmaf(x[k], W[k * H + h], acc);
  out[t] = f2b(acc);
}

// ================= MFMA bf16 GEMM: C[M x 128] = [X1|X2] @ [W1;W2] =================
// optional C8: fp8 e4m3 copy of the output with its own row stride ldC8
__global__ __launch_bounds__(256) void k_mgemm(const unsigned short* __restrict__ X1, int ldX1, int K1,
                                               const unsigned short* __restrict__ W1t,
                                               const unsigned short* __restrict__ X2, int ldX2, int K2,
                                               const unsigned short* __restrict__ W2t,
                                               const float* __restrict__ bias,
                                               void* __restrict__ Cv, long ldC,
                                               int M, int flags,
                                               unsigned char* __restrict__ C8, long ldC8) {
  __shared__ unsigned short Als[64 * 40];
  __shared__ unsigned short Bls[128 * 40];
  __shared__ float rs[2][64];
  int tid = threadIdx.x;
  int lane = tid & 63, wv = tid >> 6;
  int m = lane & 15, q = lane >> 4;
  int rbase = (wv & 1) * 32;
  int cbase = (wv >> 1) * 64;
  int blockRow = blockIdx.x * 64;
  int sr = tid >> 2, skc = (tid & 3) * 8;
  f32x4 acc[2][4];
#pragma unroll
  for (int a = 0; a < 2; a++)
#pragma unroll
    for (int b = 0; b < 4; b++) acc[a][b] = (f32x4){0.f, 0.f, 0.f, 0.f};

  int Ktot = K1 + K2;
  for (int k0 = 0; k0 < Ktot; k0 += 32) {
    const unsigned short* Xb;
    const unsigned short* Wt_;
    int kr, ldx, Kw;
    if (k0 < K1) { Xb = X1; Wt_ = W1t; kr = k0; ldx = ldX1; Kw = K1; }
    else { Xb = X2; Wt_ = W2t; kr = k0 - K1; ldx = ldX2; Kw = K2; }
    __syncthreads();
    {
      int gr = blockRow + sr;
      bf16x8 xv = (bf16x8){0, 0, 0, 0, 0, 0, 0, 0};
      if (gr < M) xv = *(const bf16x8*)(Xb + (size_t)gr * ldx + kr + skc);
      *(bf16x8*)&Als[sr * 40 + skc] = xv;
    }
#pragma unroll
    for (int it = 0; it < 2; it++) {
      int fid = it * 256 + tid;
      int n = fid >> 2, kc = (fid & 3) * 8;
      *(bf16x8*)&Bls[n * 40 + kc] = *(const bf16x8*)(Wt_ + (size_t)n * Kw + kr + kc);
    }
    __syncthreads();
    bf16x8 a0 = *(const bf16x8*)&Als[(rbase + m) * 40 + q * 8];
    bf16x8 a1 = *(const bf16x8*)&Als[(rbase + 16 + m) * 40 + q * 8];
    bf16x8 b0 = *(const bf16x8*)&Bls[(cbase + m) * 40 + q * 8];
    bf16x8 b1 = *(const bf16x8*)&Bls[(cbase + 16 + m) * 40 + q * 8];
    bf16x8 b2 = *(const bf16x8*)&Bls[(cbase + 32 + m) * 40 + q * 8];
    bf16x8 b3 = *(const bf16x8*)&Bls[(cbase + 48 + m) * 40 + q * 8];
    acc[0][0] = __builtin_amdgcn_mfma_f32_16x16x32_bf16(a0, b0, acc[0][0], 0, 0, 0);
    acc[0][1] = __builtin_amdgcn_mfma_f32_16x16x32_bf16(a0, b1, acc[0][1], 0, 0, 0);
    acc[0][2] = __builtin_amdgcn_mfma_f32_16x16x32_bf16(a0, b2, acc[0][2], 0, 0, 0);
    acc[0][3] = __builtin_amdgcn_mfma_f32_16x16x32_bf16(a0, b3, acc[0][3], 0, 0, 0);
    acc[1][0] = __builtin_amdgcn_mfma_f32_16x16x32_bf16(a1, b0, acc[1][0], 0, 0, 0);
    acc[1][1] = __builtin_amdgcn_mfma_f32_16x16x32_bf16(a1, b1, acc[1][1], 0, 0, 0);
    acc[1][2] = __builtin_amdgcn_mfma_f32_16x16x32_bf16(a1, b2, acc[1][2], 0, 0, 0);
    acc[1][3] = __builtin_amdgcn_mfma_f32_16x16x32_bf16(a1, b3, acc[1][3], 0, 0, 0);
  }
  float ov[2][4][4];
  float bcol[4] = {0.f, 0.f, 0.f, 0.f};
  if (bias) {
#pragma unroll
    for (int j = 0; j < 4; j++) bcol[j] = bias[cbase + j * 16 + m];
  }
#pragma unroll
  for (int a = 0; a < 2; a++)
#pragma unroll
    for (int j = 0; j < 4; j++)
#pragma unroll
      for (int i = 0; i < 4; i++) ov[a][j][i] = acc[a][j][i] + bcol[j];

  if (flags & TG_NORM) {
#pragma unroll
    for (int a = 0; a < 2; a++)
#pragma unroll
      for (int i = 0; i < 4; i++) {
        float p = 0.f;
#pragma unroll
        for (int j = 0; j < 4; j++) p = fmaf(ov[a][j][i], ov[a][j][i], p);
        p += __shfl_xor(p, 1);
        p += __shfl_xor(p, 2);
        p += __shfl_xor(p, 4);
        p += __shfl_xor(p, 8);
        if (m == 0) rs[wv >> 1][rbase + a * 16 + q * 4 + i] = p;
      }
    __syncthreads();
#pragma unroll
    for (int a = 0; a < 2; a++)
#pragma unroll
      for (int i = 0; i < 4; i++) {
        int ridx = rbase + a * 16 + q * 4 + i;
        float s = rs[0][ridx] + rs[1][ridx];
        float f = 1.f / fmaxf(sqrtf(s), 1e-12f);
#pragma unroll
        for (int j = 0; j < 4; j++) ov[a][j][i] = fmaxf(ov[a][j][i] * f, 0.f);
      }
  } else if (flags & TG_RELU) {
#pragma unroll
    for (int a = 0; a < 2; a++)
#pragma unroll
      for (int j = 0; j < 4; j++)
#pragma unroll
        for (int i = 0; i < 4; i++) ov[a][j][i] = fmaxf(ov[a][j][i], 0.f);
  }
  if (flags & TG_OUTBF16) {
    unsigned short* C = (unsigned short*)Cv;
#pragma unroll
    for (int a = 0; a < 2; a++)
#pragma unroll
      for (int i = 0; i < 4; i++) {
        int row = blockRow + rbase + a * 16 + q * 4 + i;
        if (row < M) {
#pragma unroll
          for (int j = 0; j < 4; j++)
            C[(size_t)row * ldC + cbase + j * 16 + m] = f2b(ov[a][j][i]);
        }
      }
  } else {
    float* C = (float*)Cv;
#pragma unroll
    for (int a = 0; a < 2; a++)
#pragma unroll
      for (int i = 0; i < 4; i++) {
        int row = blockRow + rbase + a * 16 + q * 4 + i;
        if (row < M) {
#pragma unroll
          for (int j = 0; j < 4; j++)
            C[(size_t)row * ldC + cbase + j * 16 + m] = ov[a][j][i];
        }
      }
  }
  if (C8) {
#pragma unroll
    for (int a = 0; a < 2; a++)
#pragma unroll
      for (int i = 0; i < 4; i++) {
        int row = blockRow + rbase + a * 16 + q * 4 + i;
        if (row < M) {
#pragma unroll
          for (int j = 0; j < 4; j++)
            C8[(size_t)row * ldC8 + cbase + j * 16 + m] = f2f8(ov[a][j][i]);
        }
      }
  }
}

static inline int mgb(int M) { return (M + 63) / 64; }

// ================= fused head =================
__global__ __launch_bounds__(256) void k_head(const float* __restrict__ X,
                                              const float* __restrict__ lw,
                                              const float* __restrict__ lb,
                                              const float* __restrict__ lwl,
                                              const float* __restrict__ lbl,
                                              float* __restrict__ z, int M) {
  __shared__ float Wl[128 * 32];
  __shared__ float Xs[8][128];
  int tid = threadIdx.x;
  for (int i = tid * 4; i < 4096; i += 1024) *(float4*)&Wl[i] = *(const float4*)&lw[i];
  int rowBase = blockIdx.x * 8;
  {
    int idx = tid * 4;
    int xr = idx >> 7, xc = idx & 127;
    int grow = rowBase + xr;
    float4 v = make_float4(0.f, 0.f, 0.f, 0.f);
    if (grow < M) v = *(const float4*)(X + (size_t)grow * H + xc);
    *(float4*)&Xs[xr][xc] = v;
  }
  __syncthreads();
  int r = tid >> 5, o = tid & 31;
  float acc = lb[o];
  for (int k = 0; k < 128; k++) acc = fmaf(Xs[r][k], Wl[k * 32 + o], acc);
  acc = fmaxf(acc, 0.f) * lwl[o];
  for (int s = 16; s > 0; s >>= 1) acc += __shfl_down(acc, s, 32);
  int grow = rowBase + r;
  if (o == 0 && grow < M) z[grow] = acc + lbl[0];
}

// ================= log_softmax =================
__global__ void k_logsoftmax(const float* __restrict__ z, float* __restrict__ out, int n) {
  __shared__ float red[256];
  int tid = threadIdx.x;
  float m = -1e30f;
  for (int i = tid; i < n; i += 256) m = fmaxf(m, z[i]);
  red[tid] = m;
  __syncthreads();
  for (int s = 128; s > 0; s >>= 1) {
    if (tid < s) red[tid] = fmaxf(red[tid], red[tid + s]);
    __syncthreads();
  }
  float mx = red[0];
  __syncthreads();
  float sum = 0.f;
  for (int i = tid; i < n; i += 256) sum += __expf(z[i] - mx);
  red[tid] = sum;
  __syncthreads();
  for (int s = 128; s > 0; s >>= 1) {
    if (tid < s) red[tid] += red[tid + s];
    __syncthreads();
  }
  float lse = mx + logf(red[0]);
  for (int i = tid; i < n; i += 256) out[i] = z[i] - lse;
}

extern "C" void kernel_launch(void* const* d_in, const int* in_sizes, int n_in,
                              void* d_out, int out_size, void* d_ws, size_t ws_size,
                              hipStream_t stream) {
  const float* game_x = (const float*)d_in[0];
  const float* state_x = (const float*)d_in[1];
  const float* pc_x = (const float*)d_in[2];
  const int* ei_vv = (const int*)d_in[3];
  const int* et_vv = (const int*)d_in[4];
  const int* ei_hist = (const int*)d_in[5];
  const float* ea_hist = (const float*)d_in[6];
  const int* ei_in = (const int*)d_in[7];
  const int* ei_ss = (const int*)d_in[8];
  const int* ei_pp = (const int*)d_in[9];
  const int* ei_ps = (const int*)d_in[10];
  const float* tag10_w = (const float*)d_in[12];
  const float* tag10_b = (const float*)d_in[13];
  const float* rgcn_w = (const float*)d_in[14];
  const float* rgcn_root = (const float*)d_in[15];
  const float* rgcn_b = (const float*)d_in[16];
  const float* gcn1_w = (const float*)d_in[17];
  const float* gcn1_b = (const float*)d_in[18];
  const float* gcn2_w = (const float*)d_in[19];
  const float* gcn2_b = (const float*)d_in[20];
  const float* rg_key_w = (const float*)d_in[21];
  const float* rg_key_b = (const float*)d_in[22];
  const float* rg_query_w = (const float*)d_in[23];
  const float* rg_query_b = (const float*)d_in[24];
  const float* rg_value_w = (const float*)d_in[25];
  const float* rg_value_b = (const float*)d_in[26];
  const float* rg_edge_w = (const float*)d_in[27];
  const float* rg_skip_w = (const float*)d_in[28];
  const float* rg_b = (const float*)d_in[29];
  const float* sage32_lw = (const float*)d_in[30];
  const float* sage32_lb = (const float*)d_in[31];
  const float* sage32_rw = (const float*)d_in[32];
  const float* sage4_lw = (const float*)d_in[33];
  const float* sage4_lb = (const float*)d_in[34];
  const float* sage4_rw = (const float*)d_in[35];
  const float* sage42_lw = (const float*)d_in[36];
  const float* sage42_lb = (const float*)d_in[37];
  const float* sage42_rw = (const float*)d_in[38];
  const float* pcs_lw = (const float*)d_in[39];
  const float* pcs_lb = (const float*)d_in[40];
  const float* pcs_rw = (const float*)d_in[41];
  const float* tag2_w = (const float*)d_in[42];
  const float* tag2_b = (const float*)d_in[43];
  const float* sage5_lw = (const float*)d_in[44];
  const float* sage5_lb = (const float*)d_in[45];
  const float* sage5_rw = (const float*)d_in[46];
  const float* lin_w = (const float*)d_in[47];
  const float* lin_b = (const float*)d_in[48];
  const float* linl_w = (const float*)d_in[49];
  const float* linl_b = (const float*)d_in[50];

  const int Evv = in_sizes[3] / 2, Eh = in_sizes[5] / 2, Ein = in_sizes[7] / 2,
            Ess = in_sizes[8] / 2, Epp = in_sizes[9] / 2, Eps = in_sizes[10] / 2;
  const int EE = Evv + Epp + Eh + Ein + Eps + Ess;
  const int NN = NG + NP + 4 * NS;

  // ---- workspace layout (bytes). Peak ~130 MB. ----
  char* base = (char*)d_ws;
  const size_t B_NGH = (size_t)NG * H * 2;
  const size_t B_NPH = (size_t)NP * H * 2;
  const size_t B_NSH = (size_t)NS * H * 2;
  unsigned short* g_tag_b = (unsigned short*)base;             // later q_b
  unsigned short* g_b = (unsigned short*)(base + B_NGH);
  char* C0 = base + 2 * B_NGH;
  uint2* tmp_pairs = (uint2*)C0;
  unsigned short* P_tag10_b = (unsigned short*)C0;
  unsigned short* G3_b = (unsigned short*)C0;
  unsigned short* xW_b = (unsigned short*)C0;
  unsigned short* p1b_b = (unsigned short*)(C0 + B_NPH);
  unsigned short* p2b_b = (unsigned short*)(C0 + 2 * B_NPH);
  unsigned short* v_b = (unsigned short*)C0;
  unsigned short* q_b = g_tag_b;
  unsigned short* P_tag2_b = (unsigned short*)C0;
  char* S0 = base + 2 * B_NGH + 46000000;
  unsigned short* S_a_b = (unsigned short*)S0;
  unsigned short* S_b_b = (unsigned short*)(S0 + B_NSH);
  unsigned short* m_buf_b = (unsigned short*)(S0 + 2 * B_NSH);
  unsigned short* kk_b = (unsigned short*)(S0 + 3 * B_NSH);
  float* Sfin = (float*)(S0 + 4 * B_NSH);
  unsigned short* Wt = (unsigned short*)(S0 + 4 * B_NSH + (size_t)NS * H * 4);
  int* ip = (int*)(S0 + 4 * B_NSH + (size_t)NS * H * 4 + 700000);
  int* rp_all = ip; ip += NN + 1;
  int* eidx_all = ip; ip += EE;
  int* table = ip; ip += 512 * 1024;   // nblkA up to 1024 (CSR_CHUNK=2048)
  int* coarseOff = ip; ip += 520;
  int* colsum = ip; ip += 512;
  float* fp = (float*)ip;
  float* dinv_all = fp; fp += NN;
  float* z = fp; fp += NS;
  unsigned char* g_tag_8 = (unsigned char*)(z + NS);        // NG*128 B
  unsigned char* qvg_8 = g_tag_8 + (size_t)NG * H;          // NG*384 B interleaved q|v|g

  // graph order: 0=vv, 1=pp, 2=hh, 3=in, 4=ps, 5=ss
  Seg6 sg;
  sg.col[0] = ei_vv + Evv;  sg.row[0] = ei_vv;
  sg.col[1] = ei_pp + Epp;  sg.row[1] = ei_pp;
  sg.col[2] = ei_hist + Eh; sg.row[2] = ei_hist;
  sg.col[3] = ei_in + Ein;  sg.row[3] = ei_in;
  sg.col[4] = ei_ps + Eps;  sg.row[4] = ei_ps;
  sg.col[5] = ei_ss + Ess;  sg.row[5] = ei_ss;
  sg.et0 = et_vv;
  int no[7] = {0, NG, NG + NP, NG + NP + NS, NG + NP + 2 * NS, NG + NP + 3 * NS, NN};
  int eo[7] = {0, Evv, Evv + Epp, Evv + Epp + Eh, Evv + Epp + Eh + Ein,
               Evv + Epp + Eh + Ein + Eps, EE};
  for (int i = 0; i < 7; i++) { sg.nodeoff[i] = no[i]; sg.edgeoff[i] = eo[i]; }
  int md[6] = {1, 0, 2, 0, 0, 0};
  float as[6] = {0.f, 1.f, 0.f, 0.f, 0.f, 0.f};
  int hd[6] = {1, 1, 0, 0, 0, 1};
  for (int i = 0; i < 6; i++) { sg.mode[i] = md[i]; sg.addself[i] = as[i]; sg.hasdinv[i] = hd[i]; }

  const int* rp_vv = rp_all + no[0];
  const int* rp_pp = rp_all + no[1];
  const int* rp_hh = rp_all + no[2];
  const int* rp_in = rp_all + no[3];
  const int* rp_ps = rp_all + no[4];
  const int* rp_ss = rp_all + no[5];
  const float* dinvG = dinv_all + no[0];
  const float* dinvP = dinv_all + no[1];
  const float* dinvS = dinv_all + no[5];
  const int* rh = ei_hist;

  // ---- weight pre-pack (transposed bf16) ----
  Pack17 pk;
  const float* wsrc[17] = {tag10_w, rgcn_w, rgcn_root, gcn2_w, rg_query_w, rg_value_w,
                           sage32_lw, sage32_rw, sage4_lw, sage4_rw, sage42_lw, sage42_rw,
                           pcs_lw, pcs_rw, tag2_w, sage5_lw, sage5_rw};
  int ksrc[17] = {28, 384, 128, 128, 128, 128, 128, 128, 128, 128, 128, 128, 128, 128, 384, 128, 128};
  int kdst[17] = {32, 384, 128, 128, 128, 128, 128, 128, 128, 128, 128, 128, 128, 128, 384, 128, 128};
  int run = 0;
  for (int i = 0; i < 17; i++) {
    pk.d[i].src = wsrc[i]; pk.d[i].Ksrc = ksrc[i]; pk.d[i].Kdst = kdst[i];
    pk.koff[i] = run; run += kdst[i];
  }
  pk.koff[17] = run;
  unsigned short* WT[17];
  for (int i = 0; i < 17; i++) WT[i] = Wt + (size_t)pk.koff[i] * 128;
  k_pack<<<nblk((long long)run * 128), 256, 0, stream>>>(pk, Wt, run);

  // ---- atomic-free CSR build (6 dispatches, fully parallel scan) ----
  int nblkA = (EE + CSR_CHUNK - 1) / CSR_CHUNK;
  int B = (NN + 511) / 512;
  k_hist<<<nblkA, 256, 0, stream>>>(sg, EE, table);
  k_scanT1<<<512, 256, 0, stream>>>(table, nblkA, colsum);
  k_scanT2<<<1, 512, 0, stream>>>(colsum, coarseOff);
  k_scanT3<<<nblk((long long)nblkA * 512), 256, 0, stream>>>(table, coarseOff, nblkA * 512);
  k_scatterA<<<nblkA, 256, 0, stream>>>(sg, EE, table, tmp_pairs);
  k_localCSR<<<B, 256, 0, stream>>>(tmp_pairs, coarseOff, sg, NN, EE, B,
                                    rp_all, eidx_all, dinv_all);

  // ================= phase 1: TAGConv game =================
  k_copy7b<<<nblk((long long)NG * 32), 256, 0, stream>>>(game_x, P_tag10_b, NG);
  k_gnorm7w<<<(NG + 3) / 4, 256, 0, stream>>>(P_tag10_b, 32, 0, eidx_all, rp_vv, dinvG,
                                              P_tag10_b, 32, 7, NG);
  k_gnorm7w<<<(NG + 3) / 4, 256, 0, stream>>>(P_tag10_b, 32, 7, eidx_all, rp_vv, dinvG,
                                              P_tag10_b, 32, 14, NG);
  k_gnorm7w<<<(NG + 3) / 4, 256, 0, stream>>>(P_tag10_b, 32, 14, eidx_all, rp_vv, dinvG,
                                              P_tag10_b, 32, 21, NG);
  k_mgemm<<<mgb(NG), 256, 0, stream>>>(P_tag10_b, 32, 32, WT[0], nullptr, 0, 0, nullptr,
                                       tag10_b, g_tag_b, H, NG, TG_RELU | TG_OUTBF16,
                                       g_tag_8, H);

  // ================= phase 2: RGCN (fp8 rel-gather + dual-K GEMM) =================
  k_grel3<<<(NG + 3) / 4, 256, 0, stream>>>(g_tag_8, eidx_all, rp_vv, G3_b, NG);
  k_mgemm<<<mgb(NG), 256, 0, stream>>>(G3_b, 384, 384, WT[1], g_tag_b, H, H, WT[2],
                                       rgcn_b, g_b, H, NG, TG_RELU | TG_OUTBF16,
                                       qvg_8 + 256, 384);

  // ================= phase 3: pc graph (2x GCN) =================
  k_gemm128b<<<nblk((long long)NP * H), 256, 0, stream>>>(pc_x, gcn1_w, nullptr, xW_b, NP, 5);
  k_gnorm<<<(NP + 3) / 4, 256, 0, stream>>>(xW_b, H, 0, eidx_all, rp_pp, dinvP, xW_b, gcn1_b,
                                            p1b_b, H, 0, 1, NP);
  k_mgemm<<<mgb(NP), 256, 0, stream>>>(p1b_b, H, H, WT[3], nullptr, 0, 0, nullptr,
                                       nullptr, xW_b, H, NP, TG_OUTBF16, nullptr, 0);
  k_gnorm<<<(NP + 3) / 4, 256, 0, stream>>>(xW_b, H, 0, eidx_all, rp_pp, dinvP, xW_b, gcn2_b,
                                            p2b_b, H, 0, 1, NP);

  // ================= phase 4: ResGated + hh-mean (fused, interleaved fp8 qvg) =======
  k_gemm128b<<<nblk((long long)NS * H), 256, 0, stream>>>(state_x, rg_key_w, rg_key_b, kk_b, NS, 6);
  k_mgemm<<<mgb(NG), 256, 0, stream>>>(g_b, H, H, WT[4], nullptr, 0, 0, nullptr,
                                       rg_query_b, q_b, H, NG, TG_OUTBF16, qvg_8, 384);
  k_mgemm<<<mgb(NG), 256, 0, stream>>>(g_b, H, H, WT[5], nullptr, 0, 0, nullptr,
                                       rg_value_b, v_b, H, NG, TG_OUTBF16, qvg_8 + 128, 384);
  k_resgated_mean<<<(NS + 3) / 4, 256, 0, stream>>>(kk_b, qvg_8, ea_hist, rg_edge_w, rh,
                                                    eidx_all, rp_hh, state_x, rg_skip_w, rg_b,
                                                    S_a_b, m_buf_b, NS);

  // ================= phase 5: sage32 =================
  k_mgemm<<<mgb(NS), 256, 0, stream>>>(m_buf_b, H, H, WT[6], S_a_b, H, H, WT[7],
                                       sage32_lb, S_b_b, H, NS, TG_NORM | TG_OUTBF16, nullptr, 0);

  // ================= phase 6: sage4 + sage42 (in, shared fp8 mean of g plane) =======
  k_gmean_f8<<<(NS + 3) / 4, 256, 0, stream>>>(qvg_8, 384, 256, eidx_all, rp_in, m_buf_b, NS);
  k_mgemm<<<mgb(NS), 256, 0, stream>>>(m_buf_b, H, H, WT[8], S_b_b, H, H, WT[9],
                                       sage4_lb, S_a_b, H, NS, TG_NORM | TG_OUTBF16, nullptr, 0);
  k_mgemm<<<mgb(NS), 256, 0, stream>>>(m_buf_b, H, H, WT[10], S_a_b, H, H, WT[11],
                                       sage42_lb, S_b_b, H, NS, TG_NORM | TG_OUTBF16, nullptr, 0);

  // ================= phase 7: pcs sage =================
  k_gmean<<<(NS + 3) / 4, 256, 0, stream>>>(p2b_b, eidx_all, rp_ps, m_buf_b, NS);
  k_mgemm<<<mgb(NS), 256, 0, stream>>>(m_buf_b, H, H, WT[12], S_b_b, H, H, WT[13],
                                       pcs_lb, P_tag2_b, 384, NS, TG_NORM | TG_OUTBF16, nullptr, 0);

  // ================= phase 8: tag2 =================
  k_gnorm<<<(NS + 3) / 4, 256, 0, stream>>>(P_tag2_b, 384, 0, eidx_all, rp_ss, dinvS, nullptr,
                                            nullptr, P_tag2_b, 384, 128, 0, NS);
  k_gnorm<<<(NS + 3) / 4, 256, 0, stream>>>(P_tag2_b, 384, 128, eidx_all, rp_ss, dinvS, nullptr,
                                            nullptr, P_tag2_b, 384, 256, 0, NS);
  k_mgemm<<<mgb(NS), 256, 0, stream>>>(P_tag2_b, 384, 384, WT[14], nullptr, 0, 0, nullptr,
                                       tag2_b, S_b_b, H, NS, TG_RELU | TG_OUTBF16, nullptr, 0);

  // ================= phase 9: sage5 =================
  k_gmean<<<(NS + 3) / 4, 256, 0, stream>>>(S_b_b, eidx_all, rp_ss, m_buf_b, NS);
  k_mgemm<<<mgb(NS), 256, 0, stream>>>(m_buf_b, H, H, WT[15], S_b_b, H, H, WT[16],
                                       sage5_lb, Sfin, H, NS, TG_NORM, nullptr, 0);

  // ================= head =================
  k_head<<<(NS + 7) / 8, 256, 0, stream>>>(Sfin, lin_w, lin_b, linl_w, linl_b, z, NS);
  k_logsoftmax<<<1, 256, 0, stream>>>(z, (float*)d_out, NS);
}